// Round 4
// baseline (1614.406 us; speedup 1.0000x reference)
//
#include <hip/hip_runtime.h>

typedef unsigned short u16;
typedef float f32x4 __attribute__((ext_vector_type(4)));
typedef __bf16 bf16v8 __attribute__((ext_vector_type(8)));
typedef u16 u16x4 __attribute__((ext_vector_type(4)));

#define WAITV(n) asm volatile("s_waitcnt vmcnt(" #n ")" ::: "memory")
#define BAR() asm volatile("s_barrier" ::: "memory")
#define LGKM0() do { asm volatile("s_waitcnt lgkmcnt(0)" ::: "memory"); \
                     __builtin_amdgcn_sched_barrier(0); } while (0)

__device__ __forceinline__ u16 f2bf(float f) {
  union { float f; unsigned int u; } v; v.f = f;
  unsigned int x = v.u;
  x += 0x7fffu + ((x >> 16) & 1u);   // round-to-nearest-even
  return (u16)(x >> 16);
}

__device__ __forceinline__ int refl(int i, int n) {
  i = (i < 0) ? -i : i;
  return (i >= n) ? (2 * n - 2 - i) : i;
}

__device__ __forceinline__ void gload_lds16(const void* g, void* l) {
  __builtin_amdgcn_global_load_lds(
      (const __attribute__((address_space(1))) void*)g,
      (__attribute__((address_space(3))) void*)l, 16, 0, 0);
}

enum { EPI_BF16_BIAS = 0, EPI_F32 = 1, EPI_BF16 = 2, EPI_F32_RES = 3, EPI_GELU = 4 };

// XCD-aware bijective block remap (m204).
__device__ __forceinline__ void xcd_remap(int& bx, int& by, int& bz) {
  const int gx = gridDim.x, gy = gridDim.y;
  const int nwg = gx * gy * (int)gridDim.z;
  const int orig = ((int)blockIdx.z * gy + (int)blockIdx.y) * gx + (int)blockIdx.x;
  const int q = nwg >> 3, r = nwg & 7;
  const int xcd = orig & 7, loc = orig >> 3;
  const int swz = (xcd < r ? xcd * (q + 1) : r * (q + 1) + (xcd - r) * q) + loc;
  const int gxy = gx * gy;
  bz = swz / gxy;
  const int rem = swz - bz * gxy;
  by = rem / gx; bx = rem - by * gx;
}

// ---------------------------------------------------------------------------
// gemm256: C[m,n] = sum_k A[m,k]*Bt[n,k].  256x256 tile, BK=32, 512 thr/8 waves.
// 3 LDS buffers (96KB), 2 phases per K-tile, stage issued inside phases
// (target buffer's old reads drained 2 barriers ago -> race-free).
// vmcnt(4) once per K-tile (4 loads/thread/tile; next tile stays in flight).
// Swizzle: 16B chunk c of row r (64B rows) stored at chunk c^(r&3); applied
// to global source and ds_read address (both-sides involution).
// ---------------------------------------------------------------------------
template <int EPI>
__global__ __launch_bounds__(512, 2) void gemm256(
    const u16* __restrict__ A, const u16* __restrict__ Bt, void* __restrict__ Cp,
    const float* __restrict__ bias, int K, int Nld, long sA, long sB, long sC, long sBias)
{
  extern __shared__ __align__(16) u16 smem[];  // buf c: A at c*16384, B at +8192

  const int t = threadIdx.x;
  int bx, by, bz; xcd_remap(bx, by, bz);
  const int m0 = by * 256, n0 = bx * 256;

  const long Kb = (long)K * 2;
  const int srow = t >> 2;
  const int schunk = ((t & 3) ^ (srow & 3)) * 16;  // swizzled source byte-col
  const char* Ag = (const char*)(A + (long)bz * sA + (long)m0 * K) + (long)srow * Kb + schunk;
  const char* Bg = (const char*)(Bt + (long)bz * sB + (long)n0 * K) + (long)srow * Kb + schunk;

  auto STAGE_A = [&](int s, int kt) {
    const long ko = (long)kt * 64;
    gload_lds16(Ag + ko, &smem[s * 16384 + t * 8]);
    gload_lds16(Ag + 128 * Kb + ko, &smem[s * 16384 + 4096 + t * 8]);
  };
  auto STAGE_B = [&](int s, int kt) {
    const long ko = (long)kt * 64;
    gload_lds16(Bg + ko, &smem[s * 16384 + 8192 + t * 8]);
    gload_lds16(Bg + 128 * Kb + ko, &smem[s * 16384 + 12288 + t * 8]);
  };

  const int w = t >> 6, lane = t & 63;
  const int wm = (w >> 2) * 128, wn = (w & 3) * 64;   // 2M x 4N waves
  const int lr = lane & 15, hi = lane >> 4;
  const int rchunk = ((hi ^ (lr & 3)) * 16) >> 1;     // elem offset within row

  f32x4 acc[8][4];
  const f32x4 vzero = {0.f, 0.f, 0.f, 0.f};
#pragma unroll
  for (int i = 0; i < 8; i++)
#pragma unroll
    for (int j = 0; j < 4; j++) acc[i][j] = vzero;

  const int NT = K >> 5;
  STAGE_A(0, 0); STAGE_B(0, 0);
  STAGE_A(1, 1); STAGE_B(1, 1);
  int c = 0;

  for (int kt = 0; kt < NT; kt++) {
    if (kt + 1 < NT) { WAITV(4); } else { WAITV(0); }
    BAR();
    const int s = (c == 0) ? 2 : c - 1;   // (kt+2) % 3
    const u16* Ad = &smem[c * 16384];
    const u16* Bd = &smem[c * 16384 + 8192];
    bf16v8 a8[4], b8[4];

    // ---- phase 0: stage A(kt+2) | read a(mi0-3), b(all) | mfma upper half
    if (kt + 2 < NT) STAGE_A(s, kt + 2);
#pragma unroll
    for (int i = 0; i < 4; i++) a8[i] = *(const bf16v8*)&Ad[(wm + i * 16 + lr) * 32 + rchunk];
#pragma unroll
    for (int i = 0; i < 4; i++) b8[i] = *(const bf16v8*)&Bd[(wn + i * 16 + lr) * 32 + rchunk];
    BAR();
    LGKM0();
    __builtin_amdgcn_s_setprio(1);
#pragma unroll
    for (int mi = 0; mi < 4; mi++)
#pragma unroll
      for (int ni = 0; ni < 4; ni++)
        acc[mi][ni] = __builtin_amdgcn_mfma_f32_16x16x32_bf16(a8[mi], b8[ni], acc[mi][ni], 0, 0, 0);
    __builtin_amdgcn_s_setprio(0);
    BAR();

    // ---- phase 1: stage B(kt+2) | read a(mi4-7) | mfma lower half
    if (kt + 2 < NT) STAGE_B(s, kt + 2);
#pragma unroll
    for (int i = 0; i < 4; i++) a8[i] = *(const bf16v8*)&Ad[(wm + 64 + i * 16 + lr) * 32 + rchunk];
    BAR();
    LGKM0();
    __builtin_amdgcn_s_setprio(1);
#pragma unroll
    for (int mi = 0; mi < 4; mi++)
#pragma unroll
      for (int ni = 0; ni < 4; ni++)
        acc[4 + mi][ni] = __builtin_amdgcn_mfma_f32_16x16x32_bf16(a8[mi], b8[ni], acc[4 + mi][ni], 0, 0, 0);
    __builtin_amdgcn_s_setprio(0);
    // phase-1 end barrier merged with next tile's post-WAITV barrier
    c = (c == 2) ? 0 : c + 1;
  }

  // epilogue: col = lane&15, row = hi*4 + j within each 16x16 fragment
#pragma unroll
  for (int mi = 0; mi < 8; mi++) {
    const int r0 = m0 + wm + mi * 16 + hi * 4;
#pragma unroll
    for (int ni = 0; ni < 4; ni++) {
      const int col = n0 + wn + ni * 16 + lr;
      float bvv = 0.f;
      if constexpr (EPI == EPI_BF16_BIAS) bvv = bias[bz * sBias + col];
#pragma unroll
      for (int j = 0; j < 4; j++) {
        const long idx = (long)(r0 + j) * Nld + col;
        const float val = acc[mi][ni][j] + bvv;
        if constexpr (EPI == EPI_BF16_BIAS || EPI == EPI_BF16) {
          ((u16*)Cp + (long)bz * sC)[idx] = f2bf(val);
        } else {
          ((float*)Cp + (long)bz * sC)[idx] = val;
        }
      }
    }
  }
}

// ---------------------------------------------------------------------------
// gemm128: 128x128 tile, BK=32, 256 thr/4 waves, 3 bufs (48KB), 1 phase/tile.
// ---------------------------------------------------------------------------
template <int EPI>
__global__ __launch_bounds__(256, 2) void gemm128(
    const u16* __restrict__ A, const u16* __restrict__ Bt, void* __restrict__ Cp,
    const float* __restrict__ bias, int K, int Nld, long sA, long sB, long sC)
{
  extern __shared__ __align__(16) u16 smem[];  // buf c: A at c*8192, B at +4096

  const int t = threadIdx.x;
  int bx, by, bz; xcd_remap(bx, by, bz);
  const int m0 = by * 128, n0 = bx * 128;

  const long Kb = (long)K * 2;
  const int srow = t >> 2;
  const int schunk = ((t & 3) ^ (srow & 3)) * 16;
  const char* Ag = (const char*)(A + (long)bz * sA + (long)m0 * K) + (long)srow * Kb + schunk;
  const char* Bg = (const char*)(Bt + (long)bz * sB + (long)n0 * K) + (long)srow * Kb + schunk;

  auto STAGE = [&](int s, int kt) {
    const long ko = (long)kt * 64;
    gload_lds16(Ag + ko, &smem[s * 8192 + t * 8]);
    gload_lds16(Ag + 64 * Kb + ko, &smem[s * 8192 + 2048 + t * 8]);
    gload_lds16(Bg + ko, &smem[s * 8192 + 4096 + t * 8]);
    gload_lds16(Bg + 64 * Kb + ko, &smem[s * 8192 + 6144 + t * 8]);
  };

  const int w = t >> 6, lane = t & 63;
  const int wm = (w >> 1) * 64, wn = (w & 1) * 64;    // 2M x 2N waves
  const int lr = lane & 15, hi = lane >> 4;
  const int rchunk = ((hi ^ (lr & 3)) * 16) >> 1;

  f32x4 acc[4][4];
  const f32x4 vzero = {0.f, 0.f, 0.f, 0.f};
#pragma unroll
  for (int i = 0; i < 4; i++)
#pragma unroll
    for (int j = 0; j < 4; j++) acc[i][j] = vzero;

  const int NT = K >> 5;
  STAGE(0, 0); STAGE(1, 1);
  int c = 0;

  for (int kt = 0; kt < NT; kt++) {
    if (kt + 1 < NT) { WAITV(4); } else { WAITV(0); }
    BAR();
    const int s = (c == 0) ? 2 : c - 1;
    const u16* Ad = &smem[c * 8192];
    const u16* Bd = &smem[c * 8192 + 4096];
    if (kt + 2 < NT) STAGE(s, kt + 2);
    bf16v8 a8[4], b8[4];
#pragma unroll
    for (int i = 0; i < 4; i++) a8[i] = *(const bf16v8*)&Ad[(wm + i * 16 + lr) * 32 + rchunk];
#pragma unroll
    for (int i = 0; i < 4; i++) b8[i] = *(const bf16v8*)&Bd[(wn + i * 16 + lr) * 32 + rchunk];
    BAR();
    LGKM0();
    __builtin_amdgcn_s_setprio(1);
#pragma unroll
    for (int mi = 0; mi < 4; mi++)
#pragma unroll
      for (int ni = 0; ni < 4; ni++)
        acc[mi][ni] = __builtin_amdgcn_mfma_f32_16x16x32_bf16(a8[mi], b8[ni], acc[mi][ni], 0, 0, 0);
    __builtin_amdgcn_s_setprio(0);
    c = (c == 2) ? 0 : c + 1;
  }

#pragma unroll
  for (int mi = 0; mi < 4; mi++) {
    const int r0 = m0 + wm + mi * 16 + hi * 4;
#pragma unroll
    for (int ni = 0; ni < 4; ni++) {
      const int col = n0 + wn + ni * 16 + lr;
      float bvv = 0.f;
      if constexpr (EPI == EPI_F32_RES || EPI == EPI_GELU) bvv = bias[col];
#pragma unroll
      for (int j = 0; j < 4; j++) {
        const long idx = (long)(r0 + j) * Nld + col;
        const float val = acc[mi][ni][j] + bvv;
        if constexpr (EPI == EPI_F32) {
          ((float*)Cp + (long)bz * sC)[idx] = val;
        } else if constexpr (EPI == EPI_F32_RES) {
          ((float*)Cp)[idx] += val;
        } else if constexpr (EPI == EPI_GELU) {
          const float gv = 0.5f * val * (1.f + erff(val * 0.70710678118654752440f));
          ((u16*)Cp)[idx] = f2bf(gv);
        } else {
          ((u16*)Cp)[idx] = f2bf(val);
        }
      }
    }
  }
}

// ---------------------------------------------------------------------------
// LayerNorm: f32 [row,1024] -> bf16
// ---------------------------------------------------------------------------
__global__ __launch_bounds__(256) void ln_kernel(const float* __restrict__ X,
    const float* __restrict__ g, const float* __restrict__ be, u16* __restrict__ Y)
{
  const long row = blockIdx.x;
  const int t = threadIdx.x;
  const float* xr = X + row * 1024;
  f32x4 v = *(const f32x4*)&xr[t * 4];
  float s = v[0] + v[1] + v[2] + v[3];
  float q = v[0]*v[0] + v[1]*v[1] + v[2]*v[2] + v[3]*v[3];
#pragma unroll
  for (int off = 32; off; off >>= 1) { s += __shfl_xor(s, off); q += __shfl_xor(q, off); }
  __shared__ float red[8];
  if ((t & 63) == 0) { red[t >> 6] = s; red[4 + (t >> 6)] = q; }
  __syncthreads();
  s = red[0] + red[1] + red[2] + red[3];
  q = red[4] + red[5] + red[6] + red[7];
  const float mean = s * (1.f / 1024.f);
  const float rstd = rsqrtf(q * (1.f / 1024.f) - mean * mean + 1e-5f);
  f32x4 gv = *(const f32x4*)&g[t * 4];
  f32x4 bv = *(const f32x4*)&be[t * 4];
  u16x4 o;
#pragma unroll
  for (int i = 0; i < 4; i++) o[i] = f2bf((v[i] - mean) * rstd * gv[i] + bv[i]);
  *(u16x4*)&Y[row * 1024 + t * 4] = o;
}

// ---------------------------------------------------------------------------
// Patch (reflect-pad + unfold) -> f32 x buffer; pad rows zeroed. rows=1280/b
// ---------------------------------------------------------------------------
__global__ __launch_bounds__(256) void patch_kernel(const float* __restrict__ img,
    float* __restrict__ X, int shift)
{
  const int n = blockIdx.x, b = blockIdx.y, t = threadIdx.x;
  float* xr = X + ((long)b * 1280 + n) * 1024;
  if (n >= 1089) {
    const f32x4 z = {0.f, 0.f, 0.f, 0.f};
    *(f32x4*)&xr[t * 4] = z;
    return;
  }
  const int p = shift * 2;
  const int ph = n / 33, pw = n - ph * 33;
  const int d0 = t * 4;
  const int c = d0 >> 6, kh = (d0 >> 3) & 7, kw0 = d0 & 7;
  const int hh = refl(ph * 8 + kh - p, 256);
  const float* src = img + ((long)(b * 16 + c) * 256 + hh) * 256;
  f32x4 v;
#pragma unroll
  for (int i = 0; i < 4; i++) v[i] = src[refl(pw * 8 + kw0 + i - p, 256)];
  *(f32x4*)&xr[d0] = v;
}

// ---------------------------------------------------------------------------
// Patch + LayerNorm fused -> bf16 (K and V inputs)
// ---------------------------------------------------------------------------
__global__ __launch_bounds__(256) void patch_ln_kernel(const float* __restrict__ img,
    const float* __restrict__ g, const float* __restrict__ be, u16* __restrict__ Y, int shift)
{
  const int n = blockIdx.x, b = blockIdx.y, t = threadIdx.x;
  u16* yr = Y + ((long)b * 1280 + n) * 1024;
  if (n >= 1089) {
    const u16x4 z = {0, 0, 0, 0};
    *(u16x4*)&yr[t * 4] = z;
    return;
  }
  const int p = shift * 2;
  const int ph = n / 33, pw = n - ph * 33;
  const int d0 = t * 4;
  const int c = d0 >> 6, kh = (d0 >> 3) & 7, kw0 = d0 & 7;
  const int hh = refl(ph * 8 + kh - p, 256);
  const float* src = img + ((long)(b * 16 + c) * 256 + hh) * 256;
  float v[4];
#pragma unroll
  for (int i = 0; i < 4; i++) v[i] = src[refl(pw * 8 + kw0 + i - p, 256)];
  float s = v[0] + v[1] + v[2] + v[3];
  float q = v[0]*v[0] + v[1]*v[1] + v[2]*v[2] + v[3]*v[3];
#pragma unroll
  for (int off = 32; off; off >>= 1) { s += __shfl_xor(s, off); q += __shfl_xor(q, off); }
  __shared__ float red[8];
  if ((t & 63) == 0) { red[t >> 6] = s; red[4 + (t >> 6)] = q; }
  __syncthreads();
  s = red[0] + red[1] + red[2] + red[3];
  q = red[4] + red[5] + red[6] + red[7];
  const float mean = s * (1.f / 1024.f);
  const float rstd = rsqrtf(q * (1.f / 1024.f) - mean * mean + 1e-5f);
  u16x4 o;
#pragma unroll
  for (int i = 0; i < 4; i++) o[i] = f2bf((v[i] - mean) * rstd * g[d0 + i] + be[d0 + i]);
  *(u16x4*)&yr[d0] = o;
}

// ---------------------------------------------------------------------------
// Row softmax with masking (valid cols < 1089), scale 1/32, bf16 out. 1280 cols
// ---------------------------------------------------------------------------
__global__ __launch_bounds__(256) void softmax_kernel(const float* __restrict__ L,
    u16* __restrict__ P)
{
  const int r = blockIdx.x, b = blockIdx.y, t = threadIdx.x;
  const float* Lr = L + ((long)b * 1280 + r) * 1280;
  u16* Pr = P + ((long)b * 1280 + r) * 1280;
  float v[5];
  float mx = -1e30f;
#pragma unroll
  for (int i = 0; i < 5; i++) {
    const int j = t + i * 256;
    v[i] = (j < 1089) ? Lr[j] * 0.03125f : -1e30f;
    mx = fmaxf(mx, v[i]);
  }
#pragma unroll
  for (int off = 32; off; off >>= 1) mx = fmaxf(mx, __shfl_xor(mx, off));
  __shared__ float sm[4];
  if ((t & 63) == 0) sm[t >> 6] = mx;
  __syncthreads();
  mx = fmaxf(fmaxf(sm[0], sm[1]), fmaxf(sm[2], sm[3]));
  float p[5];
  float s = 0.f;
#pragma unroll
  for (int i = 0; i < 5; i++) {
    const int j = t + i * 256;
    p[i] = (j < 1089) ? __expf(v[i] - mx) : 0.f;
    s += p[i];
  }
#pragma unroll
  for (int off = 32; off; off >>= 1) s += __shfl_xor(s, off);
  __shared__ float ss[4];
  if ((t & 63) == 0) ss[t >> 6] = s;
  __syncthreads();
  const float inv = 1.f / (ss[0] + ss[1] + ss[2] + ss[3]);
#pragma unroll
  for (int i = 0; i < 5; i++) Pr[t + i * 256] = f2bf(p[i] * inv);
}

// ---------------------------------------------------------------------------
// Transposes
// ---------------------------------------------------------------------------
__global__ __launch_bounds__(256) void vtrans_kernel(const u16* __restrict__ V,
    u16* __restrict__ Vt)
{
  __shared__ u16 tile[32][33];
  const int b = blockIdx.z;
  const int d0 = blockIdx.x * 32, m0 = blockIdx.y * 32;
  const int tx = threadIdx.x & 31, ty = threadIdx.x >> 5;
  const u16* Vb = V + (long)b * 1280 * 3072;
  u16* Vtb = Vt + (long)b * 3072 * 1280;
#pragma unroll
  for (int i = 0; i < 4; i++)
    tile[ty + 8 * i][tx] = Vb[(long)(m0 + ty + 8 * i) * 3072 + d0 + tx];
  __syncthreads();
#pragma unroll
  for (int i = 0; i < 4; i++)
    Vtb[(long)(d0 + ty + 8 * i) * 1280 + m0 + tx] = tile[tx][ty + 8 * i];
}

__global__ __launch_bounds__(256) void wtrans_kernel(const float* __restrict__ W,
    u16* __restrict__ Wt, int K, int N)
{
  __shared__ float tile[32][33];
  const int n0 = blockIdx.x * 32, k0 = blockIdx.y * 32;
  const int tx = threadIdx.x & 31, ty = threadIdx.x >> 5;
#pragma unroll
  for (int i = 0; i < 4; i++)
    tile[ty + 8 * i][tx] = W[(long)(k0 + ty + 8 * i) * N + n0 + tx];
  __syncthreads();
#pragma unroll
  for (int i = 0; i < 4; i++)
    Wt[(long)(n0 + ty + 8 * i) * K + k0 + tx] = f2bf(tile[tx][ty + 8 * i]);
}

__global__ __launch_bounds__(256) void catbias_kernel(const float* __restrict__ a,
    const float* __restrict__ b, const float* __restrict__ c, float* __restrict__ o)
{
  const int i = blockIdx.x * 256 + threadIdx.x;  // 3072
  o[i] = a[i]; o[3072 + i] = b[i]; o[6144 + i] = c[i];
}

// ---------------------------------------------------------------------------
// Unpatch (inverse unfold + crop) -> f32 output
// ---------------------------------------------------------------------------
__global__ __launch_bounds__(256) void unpatch_kernel(const float* __restrict__ X,
    float* __restrict__ out)
{
  const int idx = blockIdx.x * 256 + threadIdx.x;  // one per 4 floats
  const int w = (idx & 63) * 4;
  const int h = (idx >> 6) & 255;
  const int c = (idx >> 14) & 15;
  const int b = idx >> 18;
  const int ph = h >> 3, kh = h & 7, pw = w >> 3, kw = w & 7;
  const long row = (long)b * 1280 + ph * 33 + pw;
  const int d = c * 64 + kh * 8 + kw;
  const f32x4 v = *(const f32x4*)&X[row * 1024 + d];
  *(f32x4*)&out[((long)(b * 16 + c) * 256 + h) * 256 + w] = v;
}

// ---------------------------------------------------------------------------
extern "C" void kernel_launch(void* const* d_in, const int* in_sizes, int n_in,
                              void* d_out, int out_size, void* d_ws, size_t ws_size,
                              hipStream_t stream)
{
  (void)in_sizes; (void)n_in; (void)out_size; (void)ws_size;
  const float* dr_img = (const float*)d_in[0];
  const float* dr_ref = (const float*)d_in[1];
  const float* cl_ref = (const float*)d_in[2];
  const float* ln_g = (const float*)d_in[3];
  const float* ln_be = (const float*)d_in[4];
  const float* Wq = (const float*)d_in[5];
  const float* bq = (const float*)d_in[6];
  const float* Wk = (const float*)d_in[7];
  const float* bk = (const float*)d_in[8];
  const float* Wv = (const float*)d_in[9];
  const float* bv = (const float*)d_in[10];
  const float* Wo = (const float*)d_in[11];
  const float* bo = (const float*)d_in[12];
  const float* ffg = (const float*)d_in[13];
  const float* ffb = (const float*)d_in[14];
  const float* W1 = (const float*)d_in[15];
  const float* b1 = (const float*)d_in[16];
  const float* W2 = (const float*)d_in[17];
  const float* b2 = (const float*)d_in[18];

  const long R = 1280;                 // padded tokens per batch
  const long MR = 4 * R;               // 5120 total rows

  char* ws = (char*)d_ws;
  size_t off = 0;
  auto alloc = [&](size_t bytes) -> void* {
    void* pp = ws + off;
    off += (bytes + 255) & ~(size_t)255;
    return pp;
  };
  float* x    = (float*)alloc((size_t)MR * 1024 * 4);
  u16* xkv_ln = (u16*)alloc((size_t)3 * MR * 1024 * 2);  // slot1 aliased: FF hidden
  u16* qkv    = (u16*)alloc((size_t)3 * MR * 3072 * 2);  // q / k(=vpt) / v ; q also attn_out
  float* lgt  = (float*)alloc((size_t)4 * R * R * 4);
  u16* P      = (u16*)alloc((size_t)4 * R * R * 2);
  u16* Wqkv_t = (u16*)alloc((size_t)3 * 3072 * 1024 * 2);
  u16* Wo_t   = (u16*)alloc((size_t)1024 * 3072 * 2);
  u16* W1_t   = (u16*)alloc((size_t)1024 * 1024 * 2);
  u16* W2_t   = (u16*)alloc((size_t)1024 * 1024 * 2);
  float* bcat = (float*)alloc((size_t)3 * 3072 * 4);

  u16* x_ln = xkv_ln;
  u16* h    = xkv_ln + (size_t)MR * 1024;      // FF hidden aliases k_ln slot
  u16* qp   = qkv;
  u16* kp   = qkv + (size_t)MR * 3072;         // also V^T after vtrans
  u16* vp   = qkv + (size_t)2 * MR * 3072;

  wtrans_kernel<<<dim3(96, 32), 256, 0, stream>>>(Wq, Wqkv_t, 1024, 3072);
  wtrans_kernel<<<dim3(96, 32), 256, 0, stream>>>(Wk, Wqkv_t + (size_t)3072 * 1024, 1024, 3072);
  wtrans_kernel<<<dim3(96, 32), 256, 0, stream>>>(Wv, Wqkv_t + (size_t)2 * 3072 * 1024, 1024, 3072);
  wtrans_kernel<<<dim3(32, 96), 256, 0, stream>>>(Wo, Wo_t, 3072, 1024);
  wtrans_kernel<<<dim3(32, 32), 256, 0, stream>>>(W1, W1_t, 1024, 1024);
  wtrans_kernel<<<dim3(32, 32), 256, 0, stream>>>(W2, W2_t, 1024, 1024);
  catbias_kernel<<<12, 256, 0, stream>>>(bq, bk, bv, bcat);

  patch_kernel<<<dim3(1280, 4), 256, 0, stream>>>(dr_img, x, 0);

  const long sAp = (long)MR * 1024;        // proj A slot stride
  const long sBp = (long)3072 * 1024;      // proj W slot stride
  const long sCp = (long)MR * 3072;        // proj C slot stride
  const long sQb = R * 3072;               // per-batch stride in qp/kp/vp
  const long sLb = R * R;

  for (int shift = 0; shift < 4; shift++) {
    ln_kernel<<<(int)MR, 256, 0, stream>>>(x, ln_g, ln_be, x_ln);
    patch_ln_kernel<<<dim3(1280, 4), 256, 0, stream>>>(dr_ref, ln_g, ln_be, xkv_ln + sAp, shift);
    patch_ln_kernel<<<dim3(1280, 4), 256, 0, stream>>>(cl_ref, ln_g, ln_be, xkv_ln + 2 * sAp, shift);

    // Q/K/V projections, z-batched: [5120,1024] x [3072,1024]^T -> [5120,3072]
    gemm256<EPI_BF16_BIAS><<<dim3(12, 20, 3), 512, 98304, stream>>>(
        xkv_ln, Wqkv_t, qkv, bcat, 1024, 3072, sAp, sBp, sCp, 3072);

    // logits: per batch [1280,3072] x [1280,3072]^T -> [1280,1280] f32
    gemm128<EPI_F32><<<dim3(10, 10, 4), 256, 49152, stream>>>(
        qp, kp, lgt, nullptr, 3072, 1280, sQb, sQb, sLb);

    softmax_kernel<<<dim3(1280, 4), 256, 0, stream>>>(lgt, P);
    vtrans_kernel<<<dim3(96, 40, 4), 256, 0, stream>>>(vp, kp);  // vp^T into kp

    // PV: per batch [1280,1280] x [3072,1280]^T -> [1280,3072] bf16 (into qp)
    gemm256<EPI_BF16><<<dim3(12, 5, 4), 512, 98304, stream>>>(
        P, kp, qp, nullptr, 1280, 3072, sLb, (long)3072 * R, sQb, 0);

    // out-proj + residual: [5120,3072] x [1024,3072]^T -> += x
    gemm128<EPI_F32_RES><<<dim3(8, 40, 1), 256, 49152, stream>>>(
        qp, Wo_t, x, bo, 3072, 1024, 0, 0, 0);

    ln_kernel<<<(int)MR, 256, 0, stream>>>(x, ffg, ffb, x_ln);
    gemm128<EPI_GELU><<<dim3(8, 40, 1), 256, 49152, stream>>>(
        x_ln, W1_t, h, b1, 1024, 1024, 0, 0, 0);
    gemm128<EPI_F32_RES><<<dim3(8, 40, 1), 256, 49152, stream>>>(
        h, W2_t, x, b2, 1024, 1024, 0, 0, 0);
  }

  unpatch_kernel<<<4096, 256, 0, stream>>>(x, (float*)d_out);
}

// Round 5
// 1486.418 us; speedup vs baseline: 1.0861x; 1.0861x over previous
//
#include <hip/hip_runtime.h>

typedef unsigned short u16;
typedef float f32x4 __attribute__((ext_vector_type(4)));
typedef __bf16 bf16v8 __attribute__((ext_vector_type(8)));
typedef u16 u16x4 __attribute__((ext_vector_type(4)));

#define WAITV(n) asm volatile("s_waitcnt vmcnt(" #n ")" ::: "memory")
#define BAR() asm volatile("s_barrier" ::: "memory")
#define LGKM0() do { asm volatile("s_waitcnt lgkmcnt(0)" ::: "memory"); \
                     __builtin_amdgcn_sched_barrier(0); } while (0)

__device__ __forceinline__ u16 f2bf(float f) {
  union { float f; unsigned int u; } v; v.f = f;
  unsigned int x = v.u;
  x += 0x7fffu + ((x >> 16) & 1u);   // round-to-nearest-even
  return (u16)(x >> 16);
}

__device__ __forceinline__ int refl(int i, int n) {
  i = (i < 0) ? -i : i;
  return (i >= n) ? (2 * n - 2 - i) : i;
}

__device__ __forceinline__ void gload_lds16(const void* g, void* l) {
  __builtin_amdgcn_global_load_lds(
      (const __attribute__((address_space(1))) void*)g,
      (__attribute__((address_space(3))) void*)l, 16, 0, 0);
}

enum { EPI_BF16_BIAS = 0, EPI_F32 = 1, EPI_BF16 = 2, EPI_F32_RES = 3, EPI_GELU = 4 };

// XCD-aware bijective block remap (m204).
__device__ __forceinline__ void xcd_remap(int& bx, int& by, int& bz) {
  const int gx = gridDim.x, gy = gridDim.y;
  const int nwg = gx * gy * (int)gridDim.z;
  const int orig = ((int)blockIdx.z * gy + (int)blockIdx.y) * gx + (int)blockIdx.x;
  const int q = nwg >> 3, r = nwg & 7;
  const int xcd = orig & 7, loc = orig >> 3;
  const int swz = (xcd < r ? xcd * (q + 1) : r * (q + 1) + (xcd - r) * q) + loc;
  const int gxy = gx * gy;
  bz = swz / gxy;
  const int rem = swz - bz * gxy;
  by = rem / gx; bx = rem - by * gx;
}

// ---------------------------------------------------------------------------
// gemm256, 8-phase: C[m,n]=sum_k A[m,k]*Bt[n,k]. 256x256, BK=64, 512thr/8waves.
// 2 LDS buffers (128 KiB). Iteration = 2 K-tiles = 8 phases.
// Phase: {ds_read quad (+B at q0) | stage 2 gloads into dead region | barrier |
//         lgkmcnt(0)+sched_barrier | setprio(1) 16 MFMA setprio(0) | barrier}.
// vmcnt(6) once per K-tile (end of ph3 / ph7), never 0 mid-loop.
// Region-death ledger (barrier-ordered):
//   B(buf) dead after q0 of its tile (read into regs); A rows i{0,2} after q1;
//   A rows i{1,3} after q3.  Stage plan per iteration i (t0=2i):
//   ph0: A-U13(t0+1->buf1)  ph1: B02(t0+2->buf0) ph2: B13(t0+2) ph3: A-U02(t0+2)
//   ph4: A-U13(t0+2->buf0)  ph5: B02(t0+3->buf1) ph6: B13(t0+3) ph7: A-U02(t0+3)
// Swizzle (round-3 verified, conflict-free): 16B chunk c of 128B row r stored
// at chunk c^(r&7); applied on global source and ds_read address.
// ---------------------------------------------------------------------------
template <int EPI>
__global__ __launch_bounds__(512, 2) void gemm256(
    const u16* __restrict__ A, const u16* __restrict__ Bt, void* __restrict__ Cp,
    const float* __restrict__ bias, int K, int Nld, long sA, long sB, long sC, long sBias)
{
  extern __shared__ __align__(16) u16 smem[];  // buf d: A at d*32768, B at d*32768+16384

  const int t = threadIdx.x;
  int bx, by, bz; xcd_remap(bx, by, bz);
  const int m0 = by * 256, n0 = bx * 256;

  const long Kb = (long)K * 2;
  const int sr8 = t >> 3;                       // 0..63 (8 threads/row)
  const int schunk = ((t & 7) ^ (sr8 & 7)) * 16;  // swizzled source byte-col
  const char* Ag = (const char*)(A + (long)bz * sA + (long)m0 * K) + (long)sr8 * Kb + schunk;
  const char* Bg = (const char*)(Bt + (long)bz * sB + (long)n0 * K) + (long)sr8 * Kb + schunk;

  // stage 2 load-rounds (rows sr8+i0*64, sr8+i1*64) of tile kt into buf d
  auto SA = [&](int d, int kt, int i0, int i1) {
    const long ko = (long)kt * 128;
    gload_lds16(Ag + (long)i0 * 64 * Kb + ko, &smem[d * 32768 + i0 * 4096 + t * 8]);
    gload_lds16(Ag + (long)i1 * 64 * Kb + ko, &smem[d * 32768 + i1 * 4096 + t * 8]);
  };
  auto SB = [&](int d, int kt, int i0, int i1) {
    const long ko = (long)kt * 128;
    gload_lds16(Bg + (long)i0 * 64 * Kb + ko, &smem[d * 32768 + 16384 + i0 * 4096 + t * 8]);
    gload_lds16(Bg + (long)i1 * 64 * Kb + ko, &smem[d * 32768 + 16384 + i1 * 4096 + t * 8]);
  };

  const int w = t >> 6, lane = t & 63;
  const int wm = (w >> 2) * 128, wn = (w & 3) * 64;   // 2M x 4N waves
  const int lr = lane & 15, hi = lane >> 4;
  // u16 offset within 64-elem row for k-sub ks: chunk (ks*4+hi)^(lr&7), 8 u16 each
  const int rc0 = ((0 * 4 + hi) ^ (lr & 7)) * 8;
  const int rc1 = ((1 * 4 + hi) ^ (lr & 7)) * 8;

  f32x4 acc[8][4];
  const f32x4 vzero = {0.f, 0.f, 0.f, 0.f};
#pragma unroll
  for (int i = 0; i < 8; i++)
#pragma unroll
    for (int j = 0; j < 4; j++) acc[i][j] = vzero;

  const int NT = K >> 6, NI = NT >> 1;

  // prologue: tile0 full -> buf0 (8 loads); tile1 B + A-U02 -> buf1 (6 loads)
  SA(0, 0, 0, 1); SA(0, 0, 2, 3); SB(0, 0, 0, 1); SB(0, 0, 2, 3);
  SB(1, 1, 0, 2); SB(1, 1, 1, 3); SA(1, 1, 0, 2);
  WAITV(6);   // tile0 landed; tile1's 6 stay in flight
  BAR();

  for (int i = 0; i < NI; i++) {
    const int t0 = 2 * i;
    const bool last = (i == NI - 1);
#pragma unroll
    for (int h = 0; h < 2; h++) {
      const u16* Ad = &smem[h * 32768];
      const u16* Bd = Ad + 16384;
      bf16v8 b8[4][2];
#pragma unroll
      for (int q = 0; q < 4; q++) {
        // ---- ds_read this phase's A quad (+ all B at q==0)
        bf16v8 a8[2][2];
#pragma unroll
        for (int j = 0; j < 2; j++) {
          const int rbase = (wm + (2 * q + j) * 16 + lr) * 64;
          a8[j][0] = *(const bf16v8*)&Ad[rbase + rc0];
          a8[j][1] = *(const bf16v8*)&Ad[rbase + rc1];
        }
        if (q == 0) {
#pragma unroll
          for (int ni = 0; ni < 4; ni++) {
            const int rbase = (wn + ni * 16 + lr) * 64;
            b8[ni][0] = *(const bf16v8*)&Bd[rbase + rc0];
            b8[ni][1] = *(const bf16v8*)&Bd[rbase + rc1];
          }
        }
        // ---- stage (into barrier-proven dead regions)
        if (h == 0) {
          if (q == 0)           SA(1, t0 + 1, 1, 3);          // A-U13 of buf1 tile
          else if (!last) {
            if (q == 1)         SB(0, t0 + 2, 0, 2);
            else if (q == 2)    SB(0, t0 + 2, 1, 3);
            else                SA(0, t0 + 2, 0, 2);
          }
        } else if (!last) {
          if (q == 0)           SA(0, t0 + 2, 1, 3);
          else if (q == 1)      SB(1, t0 + 3, 0, 2);
          else if (q == 2)      SB(1, t0 + 3, 1, 3);
          else                  SA(1, t0 + 3, 0, 2);
        }
        BAR();
        LGKM0();
        __builtin_amdgcn_s_setprio(1);
#pragma unroll
        for (int j = 0; j < 2; j++)
#pragma unroll
          for (int ni = 0; ni < 4; ni++) {
            acc[2 * q + j][ni] = __builtin_amdgcn_mfma_f32_16x16x32_bf16(a8[j][0], b8[ni][0], acc[2 * q + j][ni], 0, 0, 0);
            acc[2 * q + j][ni] = __builtin_amdgcn_mfma_f32_16x16x32_bf16(a8[j][1], b8[ni][1], acc[2 * q + j][ni], 0, 0, 0);
          }
        __builtin_amdgcn_s_setprio(0);
        // ---- per-K-tile vmcnt before the phase-end barrier
        if (h == 0 && q == 3) { if (last) { WAITV(0); } else { WAITV(6); } }
        if (h == 1 && q == 3 && !last) { WAITV(6); }
        BAR();
      }
    }
  }

  // epilogue: col = lane&15, row = hi*4 + j within each 16x16 fragment
#pragma unroll
  for (int mi = 0; mi < 8; mi++) {
    const int r0 = m0 + wm + mi * 16 + hi * 4;
#pragma unroll
    for (int ni = 0; ni < 4; ni++) {
      const int col = n0 + wn + ni * 16 + lr;
      float bvv = 0.f;
      if constexpr (EPI == EPI_BF16_BIAS) bvv = bias[bz * sBias + col];
#pragma unroll
      for (int j = 0; j < 4; j++) {
        const long idx = (long)(r0 + j) * Nld + col;
        const float val = acc[mi][ni][j] + bvv;
        if constexpr (EPI == EPI_BF16_BIAS || EPI == EPI_BF16) {
          ((u16*)Cp + (long)bz * sC)[idx] = f2bf(val);
        } else {
          ((float*)Cp + (long)bz * sC)[idx] = val;
        }
      }
    }
  }
}

// ---------------------------------------------------------------------------
// gemm128 (round-3 proven): 128x128, BK=64, 256 thr/4 waves, 2 bufs, vmcnt(8).
// ---------------------------------------------------------------------------
template <int EPI>
__global__ __launch_bounds__(256, 2) void gemm128(
    const u16* __restrict__ A, const u16* __restrict__ Bt, void* __restrict__ Cp,
    const float* __restrict__ bias, int K, int Nld, long sA, long sB, long sC)
{
  extern __shared__ __align__(16) u16 smem[];
  u16* As = smem;            // 2 * 8192
  u16* Bs = smem + 16384;    // 2 * 8192

  const int t = threadIdx.x;
  int bx, by, bz; xcd_remap(bx, by, bz);
  const int m0 = by * 128, n0 = bx * 128;

  const long Kb = (long)K * 2;
  const int sc = ((t & 7) * 16) ^ (((t >> 3) & 7) << 4);
  const char* Ag = (const char*)(A + (long)bz * sA + (long)m0 * K) + (long)(t >> 3) * Kb + sc;
  const char* Bg = (const char*)(Bt + (long)bz * sB + (long)n0 * K) + (long)(t >> 3) * Kb + sc;

  auto STAGE = [&](int d, int kt) {
    const long ko = (long)kt * 128;
#pragma unroll
    for (int i = 0; i < 4; i++)
      gload_lds16(Ag + (long)i * 32 * Kb + ko, &As[d * 8192 + i * 2048 + t * 8]);
#pragma unroll
    for (int i = 0; i < 4; i++)
      gload_lds16(Bg + (long)i * 32 * Kb + ko, &Bs[d * 8192 + i * 2048 + t * 8]);
  };

  const int w = t >> 6, lane = t & 63;
  const int wm = (w >> 1) * 64, wn = (w & 1) * 64;    // 2M x 2N waves
  const int lr = lane & 15, hi = lane >> 4;
  const int cx = (lr & 7) << 4;

  f32x4 acc[4][4];
  const f32x4 vzero = {0.f, 0.f, 0.f, 0.f};
#pragma unroll
  for (int i = 0; i < 4; i++)
#pragma unroll
    for (int j = 0; j < 4; j++) acc[i][j] = vzero;

  const int NT = K >> 6;
  STAGE(0, 0);
  STAGE(1, 1);

  for (int kt = 0; kt < NT; kt++) {
    const int d = kt & 1;
    if (kt + 1 < NT) { WAITV(8); } else { WAITV(0); }
    BAR();

    const u16* Ad = &As[d * 8192];
    const u16* Bd = &Bs[d * 8192];
#pragma unroll
    for (int ks = 0; ks < 2; ks++) {
      bf16v8 a8[4], b8[4];
      const int cb = ks * 64;
#pragma unroll
      for (int mi = 0; mi < 4; mi++)
        a8[mi] = *(const bf16v8*)&Ad[(wm + mi * 16 + lr) * 64 + (((cb + hi * 16) ^ cx) >> 1)];
#pragma unroll
      for (int ni = 0; ni < 4; ni++)
        b8[ni] = *(const bf16v8*)&Bd[(wn + ni * 16 + lr) * 64 + (((cb + hi * 16) ^ cx) >> 1)];
      __builtin_amdgcn_s_setprio(1);
#pragma unroll
      for (int mi = 0; mi < 4; mi++)
#pragma unroll
        for (int ni = 0; ni < 4; ni++)
          acc[mi][ni] = __builtin_amdgcn_mfma_f32_16x16x32_bf16(a8[mi], b8[ni], acc[mi][ni], 0, 0, 0);
      __builtin_amdgcn_s_setprio(0);
    }
    asm volatile("s_waitcnt lgkmcnt(0)\n\ts_barrier" ::: "memory");
    if (kt + 2 < NT) STAGE(d, kt + 2);
  }

#pragma unroll
  for (int mi = 0; mi < 4; mi++) {
    const int r0 = m0 + wm + mi * 16 + hi * 4;
#pragma unroll
    for (int ni = 0; ni < 4; ni++) {
      const int col = n0 + wn + ni * 16 + lr;
      float bvv = 0.f;
      if constexpr (EPI == EPI_F32_RES || EPI == EPI_GELU) bvv = bias[col];
#pragma unroll
      for (int j = 0; j < 4; j++) {
        const long idx = (long)(r0 + j) * Nld + col;
        const float val = acc[mi][ni][j] + bvv;
        if constexpr (EPI == EPI_F32) {
          ((float*)Cp + (long)bz * sC)[idx] = val;
        } else if constexpr (EPI == EPI_F32_RES) {
          ((float*)Cp)[idx] += val;
        } else if constexpr (EPI == EPI_GELU) {
          const float gv = 0.5f * val * (1.f + erff(val * 0.70710678118654752440f));
          ((u16*)Cp)[idx] = f2bf(gv);
        } else {
          ((u16*)Cp)[idx] = f2bf(val);
        }
      }
    }
  }
}

// ---------------------------------------------------------------------------
// LayerNorm: f32 [row,1024] -> bf16
// ---------------------------------------------------------------------------
__global__ __launch_bounds__(256) void ln_kernel(const float* __restrict__ X,
    const float* __restrict__ g, const float* __restrict__ be, u16* __restrict__ Y)
{
  const long row = blockIdx.x;
  const int t = threadIdx.x;
  const float* xr = X + row * 1024;
  f32x4 v = *(const f32x4*)&xr[t * 4];
  float s = v[0] + v[1] + v[2] + v[3];
  float q = v[0]*v[0] + v[1]*v[1] + v[2]*v[2] + v[3]*v[3];
#pragma unroll
  for (int off = 32; off; off >>= 1) { s += __shfl_xor(s, off); q += __shfl_xor(q, off); }
  __shared__ float red[8];
  if ((t & 63) == 0) { red[t >> 6] = s; red[4 + (t >> 6)] = q; }
  __syncthreads();
  s = red[0] + red[1] + red[2] + red[3];
  q = red[4] + red[5] + red[6] + red[7];
  const float mean = s * (1.f / 1024.f);
  const float rstd = rsqrtf(q * (1.f / 1024.f) - mean * mean + 1e-5f);
  f32x4 gv = *(const f32x4*)&g[t * 4];
  f32x4 bv = *(const f32x4*)&be[t * 4];
  u16x4 o;
#pragma unroll
  for (int i = 0; i < 4; i++) o[i] = f2bf((v[i] - mean) * rstd * gv[i] + bv[i]);
  *(u16x4*)&Y[row * 1024 + t * 4] = o;
}

// ---------------------------------------------------------------------------
// Patch (reflect-pad + unfold) -> f32 x buffer; pad rows zeroed. rows=1280/b
// ---------------------------------------------------------------------------
__global__ __launch_bounds__(256) void patch_kernel(const float* __restrict__ img,
    float* __restrict__ X, int shift)
{
  const int n = blockIdx.x, b = blockIdx.y, t = threadIdx.x;
  float* xr = X + ((long)b * 1280 + n) * 1024;
  if (n >= 1089) {
    const f32x4 z = {0.f, 0.f, 0.f, 0.f};
    *(f32x4*)&xr[t * 4] = z;
    return;
  }
  const int p = shift * 2;
  const int ph = n / 33, pw = n - ph * 33;
  const int d0 = t * 4;
  const int c = d0 >> 6, kh = (d0 >> 3) & 7, kw0 = d0 & 7;
  const int hh = refl(ph * 8 + kh - p, 256);
  const float* src = img + ((long)(b * 16 + c) * 256 + hh) * 256;
  f32x4 v;
#pragma unroll
  for (int i = 0; i < 4; i++) v[i] = src[refl(pw * 8 + kw0 + i - p, 256)];
  *(f32x4*)&xr[d0] = v;
}

// ---------------------------------------------------------------------------
// Patch + LayerNorm fused -> bf16 (K and V inputs)
// ---------------------------------------------------------------------------
__global__ __launch_bounds__(256) void patch_ln_kernel(const float* __restrict__ img,
    const float* __restrict__ g, const float* __restrict__ be, u16* __restrict__ Y, int shift)
{
  const int n = blockIdx.x, b = blockIdx.y, t = threadIdx.x;
  u16* yr = Y + ((long)b * 1280 + n) * 1024;
  if (n >= 1089) {
    const u16x4 z = {0, 0, 0, 0};
    *(u16x4*)&yr[t * 4] = z;
    return;
  }
  const int p = shift * 2;
  const int ph = n / 33, pw = n - ph * 33;
  const int d0 = t * 4;
  const int c = d0 >> 6, kh = (d0 >> 3) & 7, kw0 = d0 & 7;
  const int hh = refl(ph * 8 + kh - p, 256);
  const float* src = img + ((long)(b * 16 + c) * 256 + hh) * 256;
  float v[4];
#pragma unroll
  for (int i = 0; i < 4; i++) v[i] = src[refl(pw * 8 + kw0 + i - p, 256)];
  float s = v[0] + v[1] + v[2] + v[3];
  float q = v[0]*v[0] + v[1]*v[1] + v[2]*v[2] + v[3]*v[3];
#pragma unroll
  for (int off = 32; off; off >>= 1) { s += __shfl_xor(s, off); q += __shfl_xor(q, off); }
  __shared__ float red[8];
  if ((t & 63) == 0) { red[t >> 6] = s; red[4 + (t >> 6)] = q; }
  __syncthreads();
  s = red[0] + red[1] + red[2] + red[3];
  q = red[4] + red[5] + red[6] + red[7];
  const float mean = s * (1.f / 1024.f);
  const float rstd = rsqrtf(q * (1.f / 1024.f) - mean * mean + 1e-5f);
  u16x4 o;
#pragma unroll
  for (int i = 0; i < 4; i++) o[i] = f2bf((v[i] - mean) * rstd * g[d0 + i] + be[d0 + i]);
  *(u16x4*)&yr[d0] = o;
}

// ---------------------------------------------------------------------------
// Row softmax with masking (valid cols < 1089), scale 1/32, bf16 out. 1280 cols
// ---------------------------------------------------------------------------
__global__ __launch_bounds__(256) void softmax_kernel(const float* __restrict__ L,
    u16* __restrict__ P)
{
  const int r = blockIdx.x, b = blockIdx.y, t = threadIdx.x;
  const float* Lr = L + ((long)b * 1280 + r) * 1280;
  u16* Pr = P + ((long)b * 1280 + r) * 1280;
  float v[5];
  float mx = -1e30f;
#pragma unroll
  for (int i = 0; i < 5; i++) {
    const int j = t + i * 256;
    v[i] = (j < 1089) ? Lr[j] * 0.03125f : -1e30f;
    mx = fmaxf(mx, v[i]);
  }
#pragma unroll
  for (int off = 32; off; off >>= 1) mx = fmaxf(mx, __shfl_xor(mx, off));
  __shared__ float sm[4];
  if ((t & 63) == 0) sm[t >> 6] = mx;
  __syncthreads();
  mx = fmaxf(fmaxf(sm[0], sm[1]), fmaxf(sm[2], sm[3]));
  float p[5];
  float s = 0.f;
#pragma unroll
  for (int i = 0; i < 5; i++) {
    const int j = t + i * 256;
    p[i] = (j < 1089) ? __expf(v[i] - mx) : 0.f;
    s += p[i];
  }
#pragma unroll
  for (int off = 32; off; off >>= 1) s += __shfl_xor(s, off);
  __shared__ float ss[4];
  if ((t & 63) == 0) ss[t >> 6] = s;
  __syncthreads();
  const float inv = 1.f / (ss[0] + ss[1] + ss[2] + ss[3]);
#pragma unroll
  for (int i = 0; i < 5; i++) Pr[t + i * 256] = f2bf(p[i] * inv);
}

// ---------------------------------------------------------------------------
// Transposes
// ---------------------------------------------------------------------------
__global__ __launch_bounds__(256) void vtrans_kernel(const u16* __restrict__ V,
    u16* __restrict__ Vt)
{
  __shared__ u16 tile[32][33];
  const int b = blockIdx.z;
  const int d0 = blockIdx.x * 32, m0 = blockIdx.y * 32;
  const int tx = threadIdx.x & 31, ty = threadIdx.x >> 5;
  const u16* Vb = V + (long)b * 1280 * 3072;
  u16* Vtb = Vt + (long)b * 3072 * 1280;
#pragma unroll
  for (int i = 0; i < 4; i++)
    tile[ty + 8 * i][tx] = Vb[(long)(m0 + ty + 8 * i) * 3072 + d0 + tx];
  __syncthreads();
#pragma unroll
  for (int i = 0; i < 4; i++)
    Vtb[(long)(d0 + ty + 8 * i) * 1280 + m0 + tx] = tile[tx][ty + 8 * i];
}

__global__ __launch_bounds__(256) void wtrans_kernel(const float* __restrict__ W,
    u16* __restrict__ Wt, int K, int N)
{
  __shared__ float tile[32][33];
  const int n0 = blockIdx.x * 32, k0 = blockIdx.y * 32;
  const int tx = threadIdx.x & 31, ty = threadIdx.x >> 5;
#pragma unroll
  for (int i = 0; i < 4; i++)
    tile[ty + 8 * i][tx] = W[(long)(k0 + ty + 8 * i) * N + n0 + tx];
  __syncthreads();
#pragma unroll
  for (int i = 0; i < 4; i++)
    Wt[(long)(n0 + ty + 8 * i) * K + k0 + tx] = f2bf(tile[tx][ty + 8 * i]);
}

__global__ __launch_bounds__(256) void catbias_kernel(const float* __restrict__ a,
    const float* __restrict__ b, const float* __restrict__ c, float* __restrict__ o)
{
  const int i = blockIdx.x * 256 + threadIdx.x;  // 3072
  o[i] = a[i]; o[3072 + i] = b[i]; o[6144 + i] = c[i];
}

// ---------------------------------------------------------------------------
// Unpatch (inverse unfold + crop) -> f32 output
// ---------------------------------------------------------------------------
__global__ __launch_bounds__(256) void unpatch_kernel(const float* __restrict__ X,
    float* __restrict__ out)
{
  const int idx = blockIdx.x * 256 + threadIdx.x;  // one per 4 floats
  const int w = (idx & 63) * 4;
  const int h = (idx >> 6) & 255;
  const int c = (idx >> 14) & 15;
  const int b = idx >> 18;
  const int ph = h >> 3, kh = h & 7, pw = w >> 3, kw = w & 7;
  const long row = (long)b * 1280 + ph * 33 + pw;
  const int d = c * 64 + kh * 8 + kw;
  const f32x4 v = *(const f32x4*)&X[row * 1024 + d];
  *(f32x4*)&out[((long)(b * 16 + c) * 256 + h) * 256 + w] = v;
}

// ---------------------------------------------------------------------------
extern "C" void kernel_launch(void* const* d_in, const int* in_sizes, int n_in,
                              void* d_out, int out_size, void* d_ws, size_t ws_size,
                              hipStream_t stream)
{
  (void)in_sizes; (void)n_in; (void)out_size; (void)ws_size;
  const float* dr_img = (const float*)d_in[0];
  const float* dr_ref = (const float*)d_in[1];
  const float* cl_ref = (const float*)d_in[2];
  const float* ln_g = (const float*)d_in[3];
  const float* ln_be = (const float*)d_in[4];
  const float* Wq = (const float*)d_in[5];
  const float* bq = (const float*)d_in[6];
  const float* Wk = (const float*)d_in[7];
  const float* bk = (const float*)d_in[8];
  const float* Wv = (const float*)d_in[9];
  const float* bv = (const float*)d_in[10];
  const float* Wo = (const float*)d_in[11];
  const float* bo = (const float*)d_in[12];
  const float* ffg = (const float*)d_in[13];
  const float* ffb = (const float*)d_in[14];
  const float* W1 = (const float*)d_in[15];
  const float* b1 = (const float*)d_in[16];
  const float* W2 = (const float*)d_in[17];
  const float* b2 = (const float*)d_in[18];

  const long R = 1280;                 // padded tokens per batch
  const long MR = 4 * R;               // 5120 total rows

  char* ws = (char*)d_ws;
  size_t off = 0;
  auto alloc = [&](size_t bytes) -> void* {
    void* pp = ws + off;
    off += (bytes + 255) & ~(size_t)255;
    return pp;
  };
  float* x    = (float*)alloc((size_t)MR * 1024 * 4);
  u16* xkv_ln = (u16*)alloc((size_t)3 * MR * 1024 * 2);  // slot1 aliased: FF hidden
  u16* qkv    = (u16*)alloc((size_t)3 * MR * 3072 * 2);  // q / k(=vpt) / v ; q also attn_out
  float* lgt  = (float*)alloc((size_t)4 * R * R * 4);
  u16* P      = (u16*)alloc((size_t)4 * R * R * 2);
  u16* Wqkv_t = (u16*)alloc((size_t)3 * 3072 * 1024 * 2);
  u16* Wo_t   = (u16*)alloc((size_t)1024 * 3072 * 2);
  u16* W1_t   = (u16*)alloc((size_t)1024 * 1024 * 2);
  u16* W2_t   = (u16*)alloc((size_t)1024 * 1024 * 2);
  float* bcat = (float*)alloc((size_t)3 * 3072 * 4);

  u16* x_ln = xkv_ln;
  u16* h    = xkv_ln + (size_t)MR * 1024;      // FF hidden aliases k_ln slot
  u16* qp   = qkv;
  u16* kp   = qkv + (size_t)MR * 3072;         // also V^T after vtrans
  u16* vp   = qkv + (size_t)2 * MR * 3072;

  wtrans_kernel<<<dim3(96, 32), 256, 0, stream>>>(Wq, Wqkv_t, 1024, 3072);
  wtrans_kernel<<<dim3(96, 32), 256, 0, stream>>>(Wk, Wqkv_t + (size_t)3072 * 1024, 1024, 3072);
  wtrans_kernel<<<dim3(96, 32), 256, 0, stream>>>(Wv, Wqkv_t + (size_t)2 * 3072 * 1024, 1024, 3072);
  wtrans_kernel<<<dim3(32, 96), 256, 0, stream>>>(Wo, Wo_t, 3072, 1024);
  wtrans_kernel<<<dim3(32, 32), 256, 0, stream>>>(W1, W1_t, 1024, 1024);
  wtrans_kernel<<<dim3(32, 32), 256, 0, stream>>>(W2, W2_t, 1024, 1024);
  catbias_kernel<<<12, 256, 0, stream>>>(bq, bk, bv, bcat);

  patch_kernel<<<dim3(1280, 4), 256, 0, stream>>>(dr_img, x, 0);

  const long sAp = (long)MR * 1024;        // proj A slot stride
  const long sBp = (long)3072 * 1024;      // proj W slot stride
  const long sCp = (long)MR * 3072;        // proj C slot stride
  const long sQb = R * 3072;               // per-batch stride in qp/kp/vp
  const long sLb = R * R;

  for (int shift = 0; shift < 4; shift++) {
    ln_kernel<<<(int)MR, 256, 0, stream>>>(x, ln_g, ln_be, x_ln);
    patch_ln_kernel<<<dim3(1280, 4), 256, 0, stream>>>(dr_ref, ln_g, ln_be, xkv_ln + sAp, shift);
    patch_ln_kernel<<<dim3(1280, 4), 256, 0, stream>>>(cl_ref, ln_g, ln_be, xkv_ln + 2 * sAp, shift);

    // Q/K/V projections, z-batched: [5120,1024] x [3072,1024]^T -> [5120,3072]
    gemm256<EPI_BF16_BIAS><<<dim3(12, 20, 3), 512, 131072, stream>>>(
        xkv_ln, Wqkv_t, qkv, bcat, 1024, 3072, sAp, sBp, sCp, 3072);

    // logits: per batch [1280,3072] x [1280,3072]^T -> [1280,1280] f32
    gemm128<EPI_F32><<<dim3(10, 10, 4), 256, 65536, stream>>>(
        qp, kp, lgt, nullptr, 3072, 1280, sQb, sQb, sLb);

    softmax_kernel<<<dim3(1280, 4), 256, 0, stream>>>(lgt, P);
    vtrans_kernel<<<dim3(96, 40, 4), 256, 0, stream>>>(vp, kp);  // vp^T into kp

    // PV: per batch [1280,1280] x [3072,1280]^T -> [1280,3072] bf16 (into qp)
    gemm256<EPI_BF16><<<dim3(12, 5, 4), 512, 131072, stream>>>(
        P, kp, qp, nullptr, 1280, 3072, sLb, (long)3072 * R, sQb, 0);

    // out-proj + residual: [5120,3072] x [1024,3072]^T -> += x
    gemm128<EPI_F32_RES><<<dim3(8, 40, 1), 256, 65536, stream>>>(
        qp, Wo_t, x, bo, 3072, 1024, 0, 0, 0);

    ln_kernel<<<(int)MR, 256, 0, stream>>>(x, ffg, ffb, x_ln);
    gemm128<EPI_GELU><<<dim3(8, 40, 1), 256, 65536, stream>>>(
        x_ln, W1_t, h, b1, 1024, 1024, 0, 0, 0);
    gemm128<EPI_F32_RES><<<dim3(8, 40, 1), 256, 65536, stream>>>(
        h, W2_t, x, b2, 1024, 1024, 0, 0, 0);
  }

  unpatch_kernel<<<4096, 256, 0, stream>>>(x, (float*)d_out);
}

// Round 6
// 1408.128 us; speedup vs baseline: 1.1465x; 1.0556x over previous
//
#include <hip/hip_runtime.h>

typedef unsigned short u16;
typedef float f32x4 __attribute__((ext_vector_type(4)));
typedef __bf16 bf16v8 __attribute__((ext_vector_type(8)));
typedef u16 u16x4 __attribute__((ext_vector_type(4)));

#define WAITV(n) asm volatile("s_waitcnt vmcnt(" #n ")" ::: "memory")
#define BAR() asm volatile("s_barrier" ::: "memory")
#define LGKM0() do { asm volatile("s_waitcnt lgkmcnt(0)" ::: "memory"); \
                     __builtin_amdgcn_sched_barrier(0); } while (0)

__device__ __forceinline__ u16 f2bf(float f) {
  union { float f; unsigned int u; } v; v.f = f;
  unsigned int x = v.u;
  x += 0x7fffu + ((x >> 16) & 1u);   // round-to-nearest-even
  return (u16)(x >> 16);
}

__device__ __forceinline__ int refl(int i, int n) {
  i = (i < 0) ? -i : i;
  return (i >= n) ? (2 * n - 2 - i) : i;
}

__device__ __forceinline__ void gload_lds16(const void* g, void* l) {
  __builtin_amdgcn_global_load_lds(
      (const __attribute__((address_space(1))) void*)g,
      (__attribute__((address_space(3))) void*)l, 16, 0, 0);
}

enum { EPI_BF16_BIAS = 0, EPI_F32 = 1, EPI_BF16 = 2, EPI_F32_RES = 3, EPI_GELU = 4,
       EPI_BF16_BIASROW = 5 };

// XCD-aware bijective block remap (m204).
__device__ __forceinline__ void xcd_remap(int& bx, int& by, int& bz) {
  const int gx = gridDim.x, gy = gridDim.y;
  const int nwg = gx * gy * (int)gridDim.z;
  const int orig = ((int)blockIdx.z * gy + (int)blockIdx.y) * gx + (int)blockIdx.x;
  const int q = nwg >> 3, r = nwg & 7;
  const int xcd = orig & 7, loc = orig >> 3;
  const int swz = (xcd < r ? xcd * (q + 1) : r * (q + 1) + (xcd - r) * q) + loc;
  const int gxy = gx * gy;
  bz = swz / gxy;
  const int rem = swz - bz * gxy;
  by = rem / gx; bx = rem - by * gx;
}

// ---------------------------------------------------------------------------
// gemm256, 8-phase (round-5 verified): C[m,n]=sum_k A[m,k]*Bt[n,k].
// 256x256, BK=64, 512thr/8waves, 2 LDS bufs (128KiB), vmcnt(6) 1x/K-tile.
// Swizzle: 16B chunk c of 128B row r stored at chunk c^(r&7) (both sides).
// EPI_BF16_BIASROW: bias indexed by output ROW (for transposed V-proj).
// ---------------------------------------------------------------------------
template <int EPI>
__global__ __launch_bounds__(512, 2) void gemm256(
    const u16* __restrict__ A, const u16* __restrict__ Bt, void* __restrict__ Cp,
    const float* __restrict__ bias, int K, int Nld, long sA, long sB, long sC, long sBias)
{
  extern __shared__ __align__(16) u16 smem[];  // buf d: A at d*32768, B at +16384

  const int t = threadIdx.x;
  int bx, by, bz; xcd_remap(bx, by, bz);
  const int m0 = by * 256, n0 = bx * 256;

  const long Kb = (long)K * 2;
  const int sr8 = t >> 3;                         // 0..63 (8 threads/row)
  const int schunk = ((t & 7) ^ (sr8 & 7)) * 16;  // swizzled source byte-col
  const char* Ag = (const char*)(A + (long)bz * sA + (long)m0 * K) + (long)sr8 * Kb + schunk;
  const char* Bg = (const char*)(Bt + (long)bz * sB + (long)n0 * K) + (long)sr8 * Kb + schunk;

  auto SA = [&](int d, int kt, int i0, int i1) {
    const long ko = (long)kt * 128;
    gload_lds16(Ag + (long)i0 * 64 * Kb + ko, &smem[d * 32768 + i0 * 4096 + t * 8]);
    gload_lds16(Ag + (long)i1 * 64 * Kb + ko, &smem[d * 32768 + i1 * 4096 + t * 8]);
  };
  auto SB = [&](int d, int kt, int i0, int i1) {
    const long ko = (long)kt * 128;
    gload_lds16(Bg + (long)i0 * 64 * Kb + ko, &smem[d * 32768 + 16384 + i0 * 4096 + t * 8]);
    gload_lds16(Bg + (long)i1 * 64 * Kb + ko, &smem[d * 32768 + 16384 + i1 * 4096 + t * 8]);
  };

  const int w = t >> 6, lane = t & 63;
  const int wm = (w >> 2) * 128, wn = (w & 3) * 64;   // 2M x 4N waves
  const int lr = lane & 15, hi = lane >> 4;
  const int rc0 = ((0 * 4 + hi) ^ (lr & 7)) * 8;
  const int rc1 = ((1 * 4 + hi) ^ (lr & 7)) * 8;

  f32x4 acc[8][4];
  const f32x4 vzero = {0.f, 0.f, 0.f, 0.f};
#pragma unroll
  for (int i = 0; i < 8; i++)
#pragma unroll
    for (int j = 0; j < 4; j++) acc[i][j] = vzero;

  const int NT = K >> 6, NI = NT >> 1;

  SA(0, 0, 0, 1); SA(0, 0, 2, 3); SB(0, 0, 0, 1); SB(0, 0, 2, 3);
  SB(1, 1, 0, 2); SB(1, 1, 1, 3); SA(1, 1, 0, 2);
  WAITV(6);
  BAR();

  for (int i = 0; i < NI; i++) {
    const int t0 = 2 * i;
    const bool last = (i == NI - 1);
#pragma unroll
    for (int h = 0; h < 2; h++) {
      const u16* Ad = &smem[h * 32768];
      const u16* Bd = Ad + 16384;
      bf16v8 b8[4][2];
#pragma unroll
      for (int q = 0; q < 4; q++) {
        bf16v8 a8[2][2];
#pragma unroll
        for (int j = 0; j < 2; j++) {
          const int rbase = (wm + (2 * q + j) * 16 + lr) * 64;
          a8[j][0] = *(const bf16v8*)&Ad[rbase + rc0];
          a8[j][1] = *(const bf16v8*)&Ad[rbase + rc1];
        }
        if (q == 0) {
#pragma unroll
          for (int ni = 0; ni < 4; ni++) {
            const int rbase = (wn + ni * 16 + lr) * 64;
            b8[ni][0] = *(const bf16v8*)&Bd[rbase + rc0];
            b8[ni][1] = *(const bf16v8*)&Bd[rbase + rc1];
          }
        }
        if (h == 0) {
          if (q == 0)           SA(1, t0 + 1, 1, 3);
          else if (!last) {
            if (q == 1)         SB(0, t0 + 2, 0, 2);
            else if (q == 2)    SB(0, t0 + 2, 1, 3);
            else                SA(0, t0 + 2, 0, 2);
          }
        } else if (!last) {
          if (q == 0)           SA(0, t0 + 2, 1, 3);
          else if (q == 1)      SB(1, t0 + 3, 0, 2);
          else if (q == 2)      SB(1, t0 + 3, 1, 3);
          else                  SA(1, t0 + 3, 0, 2);
        }
        BAR();
        LGKM0();
        __builtin_amdgcn_s_setprio(1);
#pragma unroll
        for (int j = 0; j < 2; j++)
#pragma unroll
          for (int ni = 0; ni < 4; ni++) {
            acc[2 * q + j][ni] = __builtin_amdgcn_mfma_f32_16x16x32_bf16(a8[j][0], b8[ni][0], acc[2 * q + j][ni], 0, 0, 0);
            acc[2 * q + j][ni] = __builtin_amdgcn_mfma_f32_16x16x32_bf16(a8[j][1], b8[ni][1], acc[2 * q + j][ni], 0, 0, 0);
          }
        __builtin_amdgcn_s_setprio(0);
        if (h == 0 && q == 3) { if (last) { WAITV(0); } else { WAITV(6); } }
        if (h == 1 && q == 3 && !last) { WAITV(6); }
        BAR();
      }
    }
  }

#pragma unroll
  for (int mi = 0; mi < 8; mi++) {
    const int r0 = m0 + wm + mi * 16 + hi * 4;
#pragma unroll
    for (int ni = 0; ni < 4; ni++) {
      const int col = n0 + wn + ni * 16 + lr;
      float bvv = 0.f;
      if constexpr (EPI == EPI_BF16_BIAS) bvv = bias[bz * sBias + col];
#pragma unroll
      for (int j = 0; j < 4; j++) {
        const long idx = (long)(r0 + j) * Nld + col;
        float val = acc[mi][ni][j] + bvv;
        if constexpr (EPI == EPI_BF16_BIASROW) val += bias[r0 + j];
        if constexpr (EPI == EPI_BF16_BIAS || EPI == EPI_BF16 || EPI == EPI_BF16_BIASROW) {
          ((u16*)Cp + (long)bz * sC)[idx] = f2bf(val);
        } else {
          ((float*)Cp + (long)bz * sC)[idx] = val;
        }
      }
    }
  }
}

// ---------------------------------------------------------------------------
// gemm128 (round-3 proven): 128x128, BK=64, 256thr/4waves, 2 bufs, vmcnt(8).
// ldb = B row stride in elements (PV consumes V^T with ldb=4608).
// ---------------------------------------------------------------------------
template <int EPI>
__global__ __launch_bounds__(256, 2) void gemm128(
    const u16* __restrict__ A, const u16* __restrict__ Bt, void* __restrict__ Cp,
    const float* __restrict__ bias, int K, int ldb, int Nld, long sA, long sB, long sC)
{
  extern __shared__ __align__(16) u16 smem[];
  u16* As = smem;            // 2 * 8192
  u16* Bs = smem + 16384;    // 2 * 8192

  const int t = threadIdx.x;
  int bx, by, bz; xcd_remap(bx, by, bz);
  const int m0 = by * 128, n0 = bx * 128;

  const long Ka = (long)K * 2;
  const long Kbb = (long)ldb * 2;
  const int sc = ((t & 7) * 16) ^ (((t >> 3) & 7) << 4);
  const char* Ag = (const char*)(A + (long)bz * sA + (long)m0 * K) + (long)(t >> 3) * Ka + sc;
  const char* Bg = (const char*)(Bt + (long)bz * sB + (long)n0 * ldb) + (long)(t >> 3) * Kbb + sc;

  auto STAGE = [&](int d, int kt) {
    const long ko = (long)kt * 128;
#pragma unroll
    for (int i = 0; i < 4; i++)
      gload_lds16(Ag + (long)i * 32 * Ka + ko, &As[d * 8192 + i * 2048 + t * 8]);
#pragma unroll
    for (int i = 0; i < 4; i++)
      gload_lds16(Bg + (long)i * 32 * Kbb + ko, &Bs[d * 8192 + i * 2048 + t * 8]);
  };

  const int w = t >> 6, lane = t & 63;
  const int wm = (w >> 1) * 64, wn = (w & 1) * 64;    // 2M x 2N waves
  const int lr = lane & 15, hi = lane >> 4;
  const int cx = (lr & 7) << 4;

  f32x4 acc[4][4];
  const f32x4 vzero = {0.f, 0.f, 0.f, 0.f};
#pragma unroll
  for (int i = 0; i < 4; i++)
#pragma unroll
    for (int j = 0; j < 4; j++) acc[i][j] = vzero;

  const int NT = K >> 6;
  STAGE(0, 0);
  STAGE(1, 1);

  for (int kt = 0; kt < NT; kt++) {
    const int d = kt & 1;
    if (kt + 1 < NT) { WAITV(8); } else { WAITV(0); }
    BAR();

    const u16* Ad = &As[d * 8192];
    const u16* Bd = &Bs[d * 8192];
#pragma unroll
    for (int ks = 0; ks < 2; ks++) {
      bf16v8 a8[4], b8[4];
      const int cb = ks * 64;
#pragma unroll
      for (int mi = 0; mi < 4; mi++)
        a8[mi] = *(const bf16v8*)&Ad[(wm + mi * 16 + lr) * 64 + (((cb + hi * 16) ^ cx) >> 1)];
#pragma unroll
      for (int ni = 0; ni < 4; ni++)
        b8[ni] = *(const bf16v8*)&Bd[(wn + ni * 16 + lr) * 64 + (((cb + hi * 16) ^ cx) >> 1)];
      __builtin_amdgcn_s_setprio(1);
#pragma unroll
      for (int mi = 0; mi < 4; mi++)
#pragma unroll
        for (int ni = 0; ni < 4; ni++)
          acc[mi][ni] = __builtin_amdgcn_mfma_f32_16x16x32_bf16(a8[mi], b8[ni], acc[mi][ni], 0, 0, 0);
      __builtin_amdgcn_s_setprio(0);
    }
    asm volatile("s_waitcnt lgkmcnt(0)\n\ts_barrier" ::: "memory");
    if (kt + 2 < NT) STAGE(d, kt + 2);
  }

#pragma unroll
  for (int mi = 0; mi < 4; mi++) {
    const int r0 = m0 + wm + mi * 16 + hi * 4;
#pragma unroll
    for (int ni = 0; ni < 4; ni++) {
      const int col = n0 + wn + ni * 16 + lr;
      float bvv = 0.f;
      if constexpr (EPI == EPI_F32_RES || EPI == EPI_GELU) bvv = bias[col];
#pragma unroll
      for (int j = 0; j < 4; j++) {
        const long idx = (long)(r0 + j) * Nld + col;
        const float val = acc[mi][ni][j] + bvv;
        if constexpr (EPI == EPI_F32) {
          ((float*)Cp + (long)bz * sC)[idx] = val;
        } else if constexpr (EPI == EPI_F32_RES) {
          ((float*)Cp + (long)bz * sC)[idx] += val;
        } else if constexpr (EPI == EPI_GELU) {
          const float gv = 0.5f * val * (1.f + erff(val * 0.70710678118654752440f));
          ((u16*)Cp + (long)bz * sC)[idx] = f2bf(gv);
        } else {
          ((u16*)Cp + (long)bz * sC)[idx] = f2bf(val);
        }
      }
    }
  }
}

// ---------------------------------------------------------------------------
// LayerNorm: f32 [row,1024] -> bf16
// ---------------------------------------------------------------------------
__global__ __launch_bounds__(256) void ln_kernel(const float* __restrict__ X,
    const float* __restrict__ g, const float* __restrict__ be, u16* __restrict__ Y)
{
  const long row = blockIdx.x;
  const int t = threadIdx.x;
  const float* xr = X + row * 1024;
  f32x4 v = *(const f32x4*)&xr[t * 4];
  float s = v[0] + v[1] + v[2] + v[3];
  float q = v[0]*v[0] + v[1]*v[1] + v[2]*v[2] + v[3]*v[3];
#pragma unroll
  for (int off = 32; off; off >>= 1) { s += __shfl_xor(s, off); q += __shfl_xor(q, off); }
  __shared__ float red[8];
  if ((t & 63) == 0) { red[t >> 6] = s; red[4 + (t >> 6)] = q; }
  __syncthreads();
  s = red[0] + red[1] + red[2] + red[3];
  q = red[4] + red[5] + red[6] + red[7];
  const float mean = s * (1.f / 1024.f);
  const float rstd = rsqrtf(q * (1.f / 1024.f) - mean * mean + 1e-5f);
  f32x4 gv = *(const f32x4*)&g[t * 4];
  f32x4 bv = *(const f32x4*)&be[t * 4];
  u16x4 o;
#pragma unroll
  for (int i = 0; i < 4; i++) o[i] = f2bf((v[i] - mean) * rstd * gv[i] + bv[i]);
  *(u16x4*)&Y[row * 1024 + t * 4] = o;
}

// ---------------------------------------------------------------------------
// Patch (reflect-pad + unfold) -> f32 x buffer; pad rows zeroed. rows=1152/b
// ---------------------------------------------------------------------------
__global__ __launch_bounds__(256) void patch_kernel(const float* __restrict__ img,
    float* __restrict__ X, int shift)
{
  const int n = blockIdx.x, b = blockIdx.y, t = threadIdx.x;
  float* xr = X + ((long)b * 1152 + n) * 1024;
  if (n >= 1089) {
    const f32x4 z = {0.f, 0.f, 0.f, 0.f};
    *(f32x4*)&xr[t * 4] = z;
    return;
  }
  const int p = shift * 2;
  const int ph = n / 33, pw = n - ph * 33;
  const int d0 = t * 4;
  const int c = d0 >> 6, kh = (d0 >> 3) & 7, kw0 = d0 & 7;
  const int hh = refl(ph * 8 + kh - p, 256);
  const float* src = img + ((long)(b * 16 + c) * 256 + hh) * 256;
  f32x4 v;
#pragma unroll
  for (int i = 0; i < 4; i++) v[i] = src[refl(pw * 8 + kw0 + i - p, 256)];
  *(f32x4*)&xr[d0] = v;
}

// ---------------------------------------------------------------------------
// Patch + LayerNorm fused -> bf16 (K and V inputs)
// ---------------------------------------------------------------------------
__global__ __launch_bounds__(256) void patch_ln_kernel(const float* __restrict__ img,
    const float* __restrict__ g, const float* __restrict__ be, u16* __restrict__ Y, int shift)
{
  const int n = blockIdx.x, b = blockIdx.y, t = threadIdx.x;
  u16* yr = Y + ((long)b * 1152 + n) * 1024;
  if (n >= 1089) {
    const u16x4 z = {0, 0, 0, 0};
    *(u16x4*)&yr[t * 4] = z;
    return;
  }
  const int p = shift * 2;
  const int ph = n / 33, pw = n - ph * 33;
  const int d0 = t * 4;
  const int c = d0 >> 6, kh = (d0 >> 3) & 7, kw0 = d0 & 7;
  const int hh = refl(ph * 8 + kh - p, 256);
  const float* src = img + ((long)(b * 16 + c) * 256 + hh) * 256;
  float v[4];
#pragma unroll
  for (int i = 0; i < 4; i++) v[i] = src[refl(pw * 8 + kw0 + i - p, 256)];
  float s = v[0] + v[1] + v[2] + v[3];
  float q = v[0]*v[0] + v[1]*v[1] + v[2]*v[2] + v[3]*v[3];
#pragma unroll
  for (int off = 32; off; off >>= 1) { s += __shfl_xor(s, off); q += __shfl_xor(q, off); }
  __shared__ float red[8];
  if ((t & 63) == 0) { red[t >> 6] = s; red[4 + (t >> 6)] = q; }
  __syncthreads();
  s = red[0] + red[1] + red[2] + red[3];
  q = red[4] + red[5] + red[6] + red[7];
  const float mean = s * (1.f / 1024.f);
  const float rstd = rsqrtf(q * (1.f / 1024.f) - mean * mean + 1e-5f);
  u16x4 o;
#pragma unroll
  for (int i = 0; i < 4; i++) o[i] = f2bf((v[i] - mean) * rstd * g[d0 + i] + be[d0 + i]);
  *(u16x4*)&yr[d0] = o;
}

// ---------------------------------------------------------------------------
// Row softmax, masked (valid cols < 1089), scale 1/32, bf16 out. 1152 cols.
// ---------------------------------------------------------------------------
__global__ __launch_bounds__(256) void softmax_kernel(const float* __restrict__ L,
    u16* __restrict__ P)
{
  const int r = blockIdx.x, b = blockIdx.y, t = threadIdx.x;
  const float* Lr = L + ((long)b * 1152 + r) * 1152;
  u16* Pr = P + ((long)b * 1152 + r) * 1152;
  float v[5];
  float mx = -1e30f;
#pragma unroll
  for (int i = 0; i < 5; i++) {
    const int j = t + i * 256;
    v[i] = (j < 1089) ? Lr[j] * 0.03125f : -1e30f;
    mx = fmaxf(mx, v[i]);
  }
#pragma unroll
  for (int off = 32; off; off >>= 1) mx = fmaxf(mx, __shfl_xor(mx, off));
  __shared__ float sm[4];
  if ((t & 63) == 0) sm[t >> 6] = mx;
  __syncthreads();
  mx = fmaxf(fmaxf(sm[0], sm[1]), fmaxf(sm[2], sm[3]));
  float p[5];
  float s = 0.f;
#pragma unroll
  for (int i = 0; i < 5; i++) {
    const int j = t + i * 256;
    p[i] = (j < 1089) ? __expf(v[i] - mx) : 0.f;
    s += p[i];
  }
#pragma unroll
  for (int off = 32; off; off >>= 1) s += __shfl_xor(s, off);
  __shared__ float ss[4];
  if ((t & 63) == 0) ss[t >> 6] = s;
  __syncthreads();
  const float inv = 1.f / (ss[0] + ss[1] + ss[2] + ss[3]);
#pragma unroll
  for (int i = 0; i < 5; i++) {
    const int j = t + i * 256;
    if (j < 1152) Pr[j] = f2bf(p[i] * inv);
  }
}

// ---------------------------------------------------------------------------
// Weight transpose (f32 -> bf16, W[K][N] -> Wt[N][K])
// ---------------------------------------------------------------------------
__global__ __launch_bounds__(256) void wtrans_kernel(const float* __restrict__ W,
    u16* __restrict__ Wt, int K, int N)
{
  __shared__ float tile[32][33];
  const int n0 = blockIdx.x * 32, k0 = blockIdx.y * 32;
  const int tx = threadIdx.x & 31, ty = threadIdx.x >> 5;
#pragma unroll
  for (int i = 0; i < 4; i++)
    tile[ty + 8 * i][tx] = W[(long)(k0 + ty + 8 * i) * N + n0 + tx];
  __syncthreads();
#pragma unroll
  for (int i = 0; i < 4; i++)
    Wt[(long)(n0 + ty + 8 * i) * K + k0 + tx] = f2bf(tile[tx][ty + 8 * i]);
}

__global__ __launch_bounds__(256) void catbias_kernel(const float* __restrict__ a,
    const float* __restrict__ b, const float* __restrict__ c, float* __restrict__ o)
{
  const int i = blockIdx.x * 256 + threadIdx.x;  // 3072
  o[i] = a[i]; o[3072 + i] = b[i]; o[6144 + i] = c[i];
}

// ---------------------------------------------------------------------------
// Unpatch (inverse unfold + crop) -> f32 output
// ---------------------------------------------------------------------------
__global__ __launch_bounds__(256) void unpatch_kernel(const float* __restrict__ X,
    float* __restrict__ out)
{
  const int idx = blockIdx.x * 256 + threadIdx.x;  // one per 4 floats
  const int w = (idx & 63) * 4;
  const int h = (idx >> 6) & 255;
  const int c = (idx >> 14) & 15;
  const int b = idx >> 18;
  const int ph = h >> 3, kh = h & 7, pw = w >> 3, kw = w & 7;
  const long row = (long)b * 1152 + ph * 33 + pw;
  const int d = c * 64 + kh * 8 + kw;
  const f32x4 v = *(const f32x4*)&X[row * 1024 + d];
  *(f32x4*)&out[((long)(b * 16 + c) * 256 + h) * 256 + w] = v;
}

// ---------------------------------------------------------------------------
extern "C" void kernel_launch(void* const* d_in, const int* in_sizes, int n_in,
                              void* d_out, int out_size, void* d_ws, size_t ws_size,
                              hipStream_t stream)
{
  (void)in_sizes; (void)n_in; (void)out_size; (void)ws_size;
  const float* dr_img = (const float*)d_in[0];
  const float* dr_ref = (const float*)d_in[1];
  const float* cl_ref = (const float*)d_in[2];
  const float* ln_g = (const float*)d_in[3];
  const float* ln_be = (const float*)d_in[4];
  const float* Wq = (const float*)d_in[5];
  const float* bq = (const float*)d_in[6];
  const float* Wk = (const float*)d_in[7];
  const float* bk = (const float*)d_in[8];
  const float* Wv = (const float*)d_in[9];
  const float* bv = (const float*)d_in[10];
  const float* Wo = (const float*)d_in[11];
  const float* bo = (const float*)d_in[12];
  const float* ffg = (const float*)d_in[13];
  const float* ffb = (const float*)d_in[14];
  const float* W1 = (const float*)d_in[15];
  const float* b1 = (const float*)d_in[16];
  const float* W2 = (const float*)d_in[17];
  const float* b2 = (const float*)d_in[18];

  const long R = 1152;                 // padded tokens per batch (9*128)
  const long MR = 4 * R;               // 4608 = 18*256

  char* ws = (char*)d_ws;
  size_t off = 0;
  auto alloc = [&](size_t bytes) -> void* {
    void* pp = ws + off;
    off += (bytes + 255) & ~(size_t)255;
    return pp;
  };
  float* x    = (float*)alloc((size_t)MR * 1024 * 4);
  u16* xkv_ln = (u16*)alloc((size_t)3 * MR * 1024 * 2);  // x_ln / k_ln(=FF h) / v_ln
  u16* qkv    = (u16*)alloc((size_t)3 * MR * 3072 * 2);  // q(=attn_out) / k / V^T[3072][4608]
  float* lgt  = (float*)alloc((size_t)4 * R * R * 4);
  u16* P      = (u16*)alloc((size_t)4 * R * R * 2);
  u16* Wqkv_t = (u16*)alloc((size_t)3 * 3072 * 1024 * 2);
  u16* Wo_t   = (u16*)alloc((size_t)1024 * 3072 * 2);
  u16* W1_t   = (u16*)alloc((size_t)1024 * 1024 * 2);
  u16* W2_t   = (u16*)alloc((size_t)1024 * 1024 * 2);
  float* bcat = (float*)alloc((size_t)3 * 3072 * 4);

  u16* x_ln = xkv_ln;
  u16* v_ln = xkv_ln + (size_t)2 * MR * 1024;
  u16* h    = xkv_ln + (size_t)MR * 1024;      // FF hidden aliases k_ln slot
  u16* qp   = qkv;
  u16* kp   = qkv + (size_t)MR * 3072;
  u16* vT   = qkv + (size_t)2 * MR * 3072;     // [3072][4608]
  u16* Wv_t = Wqkv_t + (size_t)2 * 3072 * 1024;

  wtrans_kernel<<<dim3(96, 32), 256, 0, stream>>>(Wq, Wqkv_t, 1024, 3072);
  wtrans_kernel<<<dim3(96, 32), 256, 0, stream>>>(Wk, Wqkv_t + (size_t)3072 * 1024, 1024, 3072);
  wtrans_kernel<<<dim3(96, 32), 256, 0, stream>>>(Wv, Wv_t, 1024, 3072);
  wtrans_kernel<<<dim3(32, 96), 256, 0, stream>>>(Wo, Wo_t, 3072, 1024);
  wtrans_kernel<<<dim3(32, 32), 256, 0, stream>>>(W1, W1_t, 1024, 1024);
  wtrans_kernel<<<dim3(32, 32), 256, 0, stream>>>(W2, W2_t, 1024, 1024);
  catbias_kernel<<<12, 256, 0, stream>>>(bq, bk, bv, bcat);

  patch_kernel<<<dim3(1152, 4), 256, 0, stream>>>(dr_img, x, 0);

  const long sAp = (long)MR * 1024;        // proj A slot stride
  const long sBp = (long)3072 * 1024;      // proj W slot stride
  const long sCp = (long)MR * 3072;        // proj C slot stride
  const long sQb = R * 3072;               // per-batch stride in qp/kp
  const long sLb = R * R;

  for (int shift = 0; shift < 4; shift++) {
    ln_kernel<<<(int)MR, 256, 0, stream>>>(x, ln_g, ln_be, x_ln);
    patch_ln_kernel<<<dim3(1152, 4), 256, 0, stream>>>(dr_ref, ln_g, ln_be, xkv_ln + sAp, shift);
    patch_ln_kernel<<<dim3(1152, 4), 256, 0, stream>>>(cl_ref, ln_g, ln_be, v_ln, shift);

    // Q/K projections, z-batched: [4608,1024] x [3072,1024]^T -> [4608,3072]
    gemm256<EPI_BF16_BIAS><<<dim3(12, 18, 2), 512, 131072, stream>>>(
        xkv_ln, Wqkv_t, qkv, bcat, 1024, 3072, sAp, sBp, sCp, 3072);

    // V^T projection (operand swap): [3072,1024] x [4608,1024]^T -> V^T[3072][4608]
    gemm256<EPI_BF16_BIASROW><<<dim3(18, 12, 1), 512, 131072, stream>>>(
        Wv_t, v_ln, vT, bv, 1024, (int)MR, 0, 0, 0, 0);

    // logits: per batch [1152,3072] x [1152,3072]^T -> [1152,1152] f32
    gemm128<EPI_F32><<<dim3(9, 9, 4), 256, 65536, stream>>>(
        qp, kp, lgt, nullptr, 3072, 3072, 1152, sQb, sQb, sLb);

    softmax_kernel<<<dim3(1152, 4), 256, 0, stream>>>(lgt, P);

    // PV: per batch [1152,1152] x V^T(ldb=4608, base offset b*1152) -> [1152,3072]
    gemm128<EPI_BF16><<<dim3(24, 9, 4), 256, 65536, stream>>>(
        P, vT, qp, nullptr, 1152, (int)MR, 3072, sLb, R, sQb);

    // out-proj + residual: [4608,3072] x [1024,3072]^T -> += x
    gemm128<EPI_F32_RES><<<dim3(8, 36, 1), 256, 65536, stream>>>(
        qp, Wo_t, x, bo, 3072, 3072, 1024, 0, 0, 0);

    ln_kernel<<<(int)MR, 256, 0, stream>>>(x, ffg, ffb, x_ln);
    gemm128<EPI_GELU><<<dim3(8, 36, 1), 256, 65536, stream>>>(
        x_ln, W1_t, h, b1, 1024, 1024, 1024, 0, 0, 0);
    gemm128<EPI_F32_RES><<<dim3(8, 36, 1), 256, 65536, stream>>>(
        h, W2_t, x, b2, 1024, 1024, 1024, 0, 0, 0);
  }

  unpatch_kernel<<<4096, 256, 0, stream>>>(x, (float*)d_out);
}

// Round 7
// 1334.127 us; speedup vs baseline: 1.2101x; 1.0555x over previous
//
#include <hip/hip_runtime.h>

typedef unsigned short u16;
typedef float f32x4 __attribute__((ext_vector_type(4)));
typedef __bf16 bf16v8 __attribute__((ext_vector_type(8)));
typedef u16 u16x4 __attribute__((ext_vector_type(4)));

#define WAITV(n) asm volatile("s_waitcnt vmcnt(" #n ")" ::: "memory")
#define BAR() asm volatile("s_barrier" ::: "memory")
#define LGKM0() do { asm volatile("s_waitcnt lgkmcnt(0)" ::: "memory"); \
                     __builtin_amdgcn_sched_barrier(0); } while (0)

__device__ __forceinline__ u16 f2bf(float f) {
  union { float f; unsigned int u; } v; v.f = f;
  unsigned int x = v.u;
  x += 0x7fffu + ((x >> 16) & 1u);   // round-to-nearest-even
  return (u16)(x >> 16);
}

__device__ __forceinline__ int refl(int i, int n) {
  i = (i < 0) ? -i : i;
  return (i >= n) ? (2 * n - 2 - i) : i;
}

__device__ __forceinline__ void gload_lds16(const void* g, void* l) {
  __builtin_amdgcn_global_load_lds(
      (const __attribute__((address_space(1))) void*)g,
      (__attribute__((address_space(3))) void*)l, 16, 0, 0);
}

enum { EPI_BF16_BIAS = 0, EPI_F32 = 1, EPI_BF16 = 2, EPI_F32_RES = 3, EPI_GELU = 4,
       EPI_BF16_BIASROW = 5 };

// XCD-aware bijective block remap (m204).
__device__ __forceinline__ void xcd_remap(int& bx, int& by, int& bz) {
  const int gx = gridDim.x, gy = gridDim.y;
  const int nwg = gx * gy * (int)gridDim.z;
  const int orig = ((int)blockIdx.z * gy + (int)blockIdx.y) * gx + (int)blockIdx.x;
  const int q = nwg >> 3, r = nwg & 7;
  const int xcd = orig & 7, loc = orig >> 3;
  const int swz = (xcd < r ? xcd * (q + 1) : r * (q + 1) + (xcd - r) * q) + loc;
  const int gxy = gx * gy;
  bz = swz / gxy;
  const int rem = swz - bz * gxy;
  by = rem / gx; bx = rem - by * gx;
}

// ---------------------------------------------------------------------------
// gemm256, 8-phase (round-5 verified): C[m,n]=sum_k A[m,k]*Bt[n,k].
// 256x256, BK=64, 512thr/8waves, 2 LDS bufs (128KiB), vmcnt(6) 1x/K-tile.
// Swizzle: 16B chunk c of 128B row r stored at chunk c^(r&7) (both sides).
// EPI_BF16_BIASROW: bias indexed by output ROW (for transposed V-proj).
// ---------------------------------------------------------------------------
template <int EPI>
__global__ __launch_bounds__(512, 2) void gemm256(
    const u16* __restrict__ A, const u16* __restrict__ Bt, void* __restrict__ Cp,
    const float* __restrict__ bias, int K, int Nld, long sA, long sB, long sC, long sBias)
{
  extern __shared__ __align__(16) u16 smem[];  // buf d: A at d*32768, B at +16384

  const int t = threadIdx.x;
  int bx, by, bz; xcd_remap(bx, by, bz);
  const int m0 = by * 256, n0 = bx * 256;

  const long Kb = (long)K * 2;
  const int sr8 = t >> 3;                         // 0..63 (8 threads/row)
  const int schunk = ((t & 7) ^ (sr8 & 7)) * 16;  // swizzled source byte-col
  const char* Ag = (const char*)(A + (long)bz * sA + (long)m0 * K) + (long)sr8 * Kb + schunk;
  const char* Bg = (const char*)(Bt + (long)bz * sB + (long)n0 * K) + (long)sr8 * Kb + schunk;

  auto SA = [&](int d, int kt, int i0, int i1) {
    const long ko = (long)kt * 128;
    gload_lds16(Ag + (long)i0 * 64 * Kb + ko, &smem[d * 32768 + i0 * 4096 + t * 8]);
    gload_lds16(Ag + (long)i1 * 64 * Kb + ko, &smem[d * 32768 + i1 * 4096 + t * 8]);
  };
  auto SB = [&](int d, int kt, int i0, int i1) {
    const long ko = (long)kt * 128;
    gload_lds16(Bg + (long)i0 * 64 * Kb + ko, &smem[d * 32768 + 16384 + i0 * 4096 + t * 8]);
    gload_lds16(Bg + (long)i1 * 64 * Kb + ko, &smem[d * 32768 + 16384 + i1 * 4096 + t * 8]);
  };

  const int w = t >> 6, lane = t & 63;
  const int wm = (w >> 2) * 128, wn = (w & 3) * 64;   // 2M x 4N waves
  const int lr = lane & 15, hi = lane >> 4;
  const int rc0 = ((0 * 4 + hi) ^ (lr & 7)) * 8;
  const int rc1 = ((1 * 4 + hi) ^ (lr & 7)) * 8;

  f32x4 acc[8][4];
  const f32x4 vzero = {0.f, 0.f, 0.f, 0.f};
#pragma unroll
  for (int i = 0; i < 8; i++)
#pragma unroll
    for (int j = 0; j < 4; j++) acc[i][j] = vzero;

  const int NT = K >> 6, NI = NT >> 1;

  SA(0, 0, 0, 1); SA(0, 0, 2, 3); SB(0, 0, 0, 1); SB(0, 0, 2, 3);
  SB(1, 1, 0, 2); SB(1, 1, 1, 3); SA(1, 1, 0, 2);
  WAITV(6);
  BAR();

  for (int i = 0; i < NI; i++) {
    const int t0 = 2 * i;
    const bool last = (i == NI - 1);
#pragma unroll
    for (int h = 0; h < 2; h++) {
      const u16* Ad = &smem[h * 32768];
      const u16* Bd = Ad + 16384;
      bf16v8 b8[4][2];
#pragma unroll
      for (int q = 0; q < 4; q++) {
        bf16v8 a8[2][2];
#pragma unroll
        for (int j = 0; j < 2; j++) {
          const int rbase = (wm + (2 * q + j) * 16 + lr) * 64;
          a8[j][0] = *(const bf16v8*)&Ad[rbase + rc0];
          a8[j][1] = *(const bf16v8*)&Ad[rbase + rc1];
        }
        if (q == 0) {
#pragma unroll
          for (int ni = 0; ni < 4; ni++) {
            const int rbase = (wn + ni * 16 + lr) * 64;
            b8[ni][0] = *(const bf16v8*)&Bd[rbase + rc0];
            b8[ni][1] = *(const bf16v8*)&Bd[rbase + rc1];
          }
        }
        if (h == 0) {
          if (q == 0)           SA(1, t0 + 1, 1, 3);
          else if (!last) {
            if (q == 1)         SB(0, t0 + 2, 0, 2);
            else if (q == 2)    SB(0, t0 + 2, 1, 3);
            else                SA(0, t0 + 2, 0, 2);
          }
        } else if (!last) {
          if (q == 0)           SA(0, t0 + 2, 1, 3);
          else if (q == 1)      SB(1, t0 + 3, 0, 2);
          else if (q == 2)      SB(1, t0 + 3, 1, 3);
          else                  SA(1, t0 + 3, 0, 2);
        }
        BAR();
        LGKM0();
        __builtin_amdgcn_s_setprio(1);
#pragma unroll
        for (int j = 0; j < 2; j++)
#pragma unroll
          for (int ni = 0; ni < 4; ni++) {
            acc[2 * q + j][ni] = __builtin_amdgcn_mfma_f32_16x16x32_bf16(a8[j][0], b8[ni][0], acc[2 * q + j][ni], 0, 0, 0);
            acc[2 * q + j][ni] = __builtin_amdgcn_mfma_f32_16x16x32_bf16(a8[j][1], b8[ni][1], acc[2 * q + j][ni], 0, 0, 0);
          }
        __builtin_amdgcn_s_setprio(0);
        if (h == 0 && q == 3) { if (last) { WAITV(0); } else { WAITV(6); } }
        if (h == 1 && q == 3 && !last) { WAITV(6); }
        BAR();
      }
    }
  }

#pragma unroll
  for (int mi = 0; mi < 8; mi++) {
    const int r0 = m0 + wm + mi * 16 + hi * 4;
#pragma unroll
    for (int ni = 0; ni < 4; ni++) {
      const int col = n0 + wn + ni * 16 + lr;
      float bvv = 0.f;
      if constexpr (EPI == EPI_BF16_BIAS) bvv = bias[bz * sBias + col];
#pragma unroll
      for (int j = 0; j < 4; j++) {
        const long idx = (long)(r0 + j) * Nld + col;
        float val = acc[mi][ni][j] + bvv;
        if constexpr (EPI == EPI_BF16_BIASROW) val += bias[r0 + j];
        if constexpr (EPI == EPI_BF16_BIAS || EPI == EPI_BF16 || EPI == EPI_BF16_BIASROW) {
          ((u16*)Cp + (long)bz * sC)[idx] = f2bf(val);
        } else {
          ((float*)Cp + (long)bz * sC)[idx] = val;
        }
      }
    }
  }
}

// ---------------------------------------------------------------------------
// gemm128 v2: 128x128 tile, BK=64, 512 thr / 8 waves (wave-tile 64x32, 2Mx4N),
// 2 LDS bufs (64KiB), counted vmcnt(4), 2-phase loop (round-3-proven scheme).
// Staging/swizzle identical to gemm256 pattern (t>>3 rows, chunk^(row&7)).
// 8 waves -> 2 waves/SIMD even at 1 block/CU; 4/SIMD at 2 blocks/CU.
// ldb = B row stride in elements (PV consumes V^T with ldb=4608).
// ---------------------------------------------------------------------------
template <int EPI>
__global__ __launch_bounds__(512, 4) void gemm128(
    const u16* __restrict__ A, const u16* __restrict__ Bt, void* __restrict__ Cp,
    const float* __restrict__ bias, int K, int ldb, int Nld, long sA, long sB, long sC)
{
  extern __shared__ __align__(16) u16 smem[];  // buf d: A at d*16384, B at +8192

  const int t = threadIdx.x;
  int bx, by, bz; xcd_remap(bx, by, bz);
  const int m0 = by * 128, n0 = bx * 128;

  const long Ka = (long)K * 2;
  const long Kb2 = (long)ldb * 2;
  const int sr8 = t >> 3;                         // 0..63
  const int schunk = ((t & 7) ^ (sr8 & 7)) * 16;  // swizzled source byte-col
  const char* Ag = (const char*)(A + (long)bz * sA + (long)m0 * K) + (long)sr8 * Ka + schunk;
  const char* Bg = (const char*)(Bt + (long)bz * sB + (long)n0 * ldb) + (long)sr8 * Kb2 + schunk;

  auto STAGE = [&](int d, int kt) {
    const long ko = (long)kt * 128;
    gload_lds16(Ag + ko,                &smem[d * 16384 + t * 8]);
    gload_lds16(Ag + 64 * Ka + ko,      &smem[d * 16384 + 4096 + t * 8]);
    gload_lds16(Bg + ko,                &smem[d * 16384 + 8192 + t * 8]);
    gload_lds16(Bg + 64 * Kb2 + ko,     &smem[d * 16384 + 12288 + t * 8]);
  };

  const int w = t >> 6, lane = t & 63;
  const int wm = (w >> 2) * 64, wn = (w & 3) * 32;   // 2M x 4N waves, 64x32 tile
  const int lr = lane & 15, hi = lane >> 4;
  const int rc0 = ((0 * 4 + hi) ^ (lr & 7)) * 8;
  const int rc1 = ((1 * 4 + hi) ^ (lr & 7)) * 8;

  f32x4 acc[4][2];
  const f32x4 vzero = {0.f, 0.f, 0.f, 0.f};
#pragma unroll
  for (int i = 0; i < 4; i++)
#pragma unroll
    for (int j = 0; j < 2; j++) acc[i][j] = vzero;

  const int NT = K >> 6;
  STAGE(0, 0);
  STAGE(1, 1);

  for (int kt = 0; kt < NT; kt++) {
    const int d = kt & 1;
    if (kt + 1 < NT) { WAITV(4); } else { WAITV(0); }
    BAR();

    const u16* Ad = &smem[d * 16384];
    const u16* Bd = Ad + 8192;
    bf16v8 a8[4][2], b8[2][2];
#pragma unroll
    for (int mi = 0; mi < 4; mi++) {
      const int rbase = (wm + mi * 16 + lr) * 64;
      a8[mi][0] = *(const bf16v8*)&Ad[rbase + rc0];
      a8[mi][1] = *(const bf16v8*)&Ad[rbase + rc1];
    }
#pragma unroll
    for (int ni = 0; ni < 2; ni++) {
      const int rbase = (wn + ni * 16 + lr) * 64;
      b8[ni][0] = *(const bf16v8*)&Bd[rbase + rc0];
      b8[ni][1] = *(const bf16v8*)&Bd[rbase + rc1];
    }
    __builtin_amdgcn_s_setprio(1);
#pragma unroll
    for (int mi = 0; mi < 4; mi++)
#pragma unroll
      for (int ni = 0; ni < 2; ni++) {
        acc[mi][ni] = __builtin_amdgcn_mfma_f32_16x16x32_bf16(a8[mi][0], b8[ni][0], acc[mi][ni], 0, 0, 0);
        acc[mi][ni] = __builtin_amdgcn_mfma_f32_16x16x32_bf16(a8[mi][1], b8[ni][1], acc[mi][ni], 0, 0, 0);
      }
    __builtin_amdgcn_s_setprio(0);
    asm volatile("s_waitcnt lgkmcnt(0)\n\ts_barrier" ::: "memory");
    if (kt + 2 < NT) STAGE(d, kt + 2);
  }

#pragma unroll
  for (int mi = 0; mi < 4; mi++) {
    const int r0 = m0 + wm + mi * 16 + hi * 4;
#pragma unroll
    for (int ni = 0; ni < 2; ni++) {
      const int col = n0 + wn + ni * 16 + lr;
      float bvv = 0.f;
      if constexpr (EPI == EPI_F32_RES || EPI == EPI_GELU) bvv = bias[col];
#pragma unroll
      for (int j = 0; j < 4; j++) {
        const long idx = (long)(r0 + j) * Nld + col;
        const float val = acc[mi][ni][j] + bvv;
        if constexpr (EPI == EPI_F32) {
          ((float*)Cp + (long)bz * sC)[idx] = val;
        } else if constexpr (EPI == EPI_F32_RES) {
          ((float*)Cp + (long)bz * sC)[idx] += val;
        } else if constexpr (EPI == EPI_GELU) {
          const float gv = 0.5f * val * (1.f + erff(val * 0.70710678118654752440f));
          ((u16*)Cp + (long)bz * sC)[idx] = f2bf(gv);
        } else {
          ((u16*)Cp + (long)bz * sC)[idx] = f2bf(val);
        }
      }
    }
  }
}

// ---------------------------------------------------------------------------
// LayerNorm: f32 [row,1024] -> bf16
// ---------------------------------------------------------------------------
__global__ __launch_bounds__(256) void ln_kernel(const float* __restrict__ X,
    const float* __restrict__ g, const float* __restrict__ be, u16* __restrict__ Y)
{
  const long row = blockIdx.x;
  const int t = threadIdx.x;
  const float* xr = X + row * 1024;
  f32x4 v = *(const f32x4*)&xr[t * 4];
  float s = v[0] + v[1] + v[2] + v[3];
  float q = v[0]*v[0] + v[1]*v[1] + v[2]*v[2] + v[3]*v[3];
#pragma unroll
  for (int off = 32; off; off >>= 1) { s += __shfl_xor(s, off); q += __shfl_xor(q, off); }
  __shared__ float red[8];
  if ((t & 63) == 0) { red[t >> 6] = s; red[4 + (t >> 6)] = q; }
  __syncthreads();
  s = red[0] + red[1] + red[2] + red[3];
  q = red[4] + red[5] + red[6] + red[7];
  const float mean = s * (1.f / 1024.f);
  const float rstd = rsqrtf(q * (1.f / 1024.f) - mean * mean + 1e-5f);
  f32x4 gv = *(const f32x4*)&g[t * 4];
  f32x4 bv = *(const f32x4*)&be[t * 4];
  u16x4 o;
#pragma unroll
  for (int i = 0; i < 4; i++) o[i] = f2bf((v[i] - mean) * rstd * gv[i] + bv[i]);
  *(u16x4*)&Y[row * 1024 + t * 4] = o;
}

// ---------------------------------------------------------------------------
// Patch (reflect-pad + unfold) -> f32 x buffer; pad rows zeroed. rows=1152/b
// ---------------------------------------------------------------------------
__global__ __launch_bounds__(256) void patch_kernel(const float* __restrict__ img,
    float* __restrict__ X, int shift)
{
  const int n = blockIdx.x, b = blockIdx.y, t = threadIdx.x;
  float* xr = X + ((long)b * 1152 + n) * 1024;
  if (n >= 1089) {
    const f32x4 z = {0.f, 0.f, 0.f, 0.f};
    *(f32x4*)&xr[t * 4] = z;
    return;
  }
  const int p = shift * 2;
  const int ph = n / 33, pw = n - ph * 33;
  const int d0 = t * 4;
  const int c = d0 >> 6, kh = (d0 >> 3) & 7, kw0 = d0 & 7;
  const int hh = refl(ph * 8 + kh - p, 256);
  const float* src = img + ((long)(b * 16 + c) * 256 + hh) * 256;
  f32x4 v;
#pragma unroll
  for (int i = 0; i < 4; i++) v[i] = src[refl(pw * 8 + kw0 + i - p, 256)];
  *(f32x4*)&xr[d0] = v;
}

// ---------------------------------------------------------------------------
// Patch + LayerNorm fused -> bf16 (K and V inputs)
// ---------------------------------------------------------------------------
__global__ __launch_bounds__(256) void patch_ln_kernel(const float* __restrict__ img,
    const float* __restrict__ g, const float* __restrict__ be, u16* __restrict__ Y, int shift)
{
  const int n = blockIdx.x, b = blockIdx.y, t = threadIdx.x;
  u16* yr = Y + ((long)b * 1152 + n) * 1024;
  if (n >= 1089) {
    const u16x4 z = {0, 0, 0, 0};
    *(u16x4*)&yr[t * 4] = z;
    return;
  }
  const int p = shift * 2;
  const int ph = n / 33, pw = n - ph * 33;
  const int d0 = t * 4;
  const int c = d0 >> 6, kh = (d0 >> 3) & 7, kw0 = d0 & 7;
  const int hh = refl(ph * 8 + kh - p, 256);
  const float* src = img + ((long)(b * 16 + c) * 256 + hh) * 256;
  float v[4];
#pragma unroll
  for (int i = 0; i < 4; i++) v[i] = src[refl(pw * 8 + kw0 + i - p, 256)];
  float s = v[0] + v[1] + v[2] + v[3];
  float q = v[0]*v[0] + v[1]*v[1] + v[2]*v[2] + v[3]*v[3];
#pragma unroll
  for (int off = 32; off; off >>= 1) { s += __shfl_xor(s, off); q += __shfl_xor(q, off); }
  __shared__ float red[8];
  if ((t & 63) == 0) { red[t >> 6] = s; red[4 + (t >> 6)] = q; }
  __syncthreads();
  s = red[0] + red[1] + red[2] + red[3];
  q = red[4] + red[5] + red[6] + red[7];
  const float mean = s * (1.f / 1024.f);
  const float rstd = rsqrtf(q * (1.f / 1024.f) - mean * mean + 1e-5f);
  u16x4 o;
#pragma unroll
  for (int i = 0; i < 4; i++) o[i] = f2bf((v[i] - mean) * rstd * g[d0 + i] + be[d0 + i]);
  *(u16x4*)&yr[d0] = o;
}

// ---------------------------------------------------------------------------
// Row softmax, masked (valid cols < 1089), scale 1/32, bf16 out. 1152 cols.
// ---------------------------------------------------------------------------
__global__ __launch_bounds__(256) void softmax_kernel(const float* __restrict__ L,
    u16* __restrict__ P)
{
  const int r = blockIdx.x, b = blockIdx.y, t = threadIdx.x;
  const float* Lr = L + ((long)b * 1152 + r) * 1152;
  u16* Pr = P + ((long)b * 1152 + r) * 1152;
  float v[5];
  float mx = -1e30f;
#pragma unroll
  for (int i = 0; i < 5; i++) {
    const int j = t + i * 256;
    v[i] = (j < 1089) ? Lr[j] * 0.03125f : -1e30f;
    mx = fmaxf(mx, v[i]);
  }
#pragma unroll
  for (int off = 32; off; off >>= 1) mx = fmaxf(mx, __shfl_xor(mx, off));
  __shared__ float sm[4];
  if ((t & 63) == 0) sm[t >> 6] = mx;
  __syncthreads();
  mx = fmaxf(fmaxf(sm[0], sm[1]), fmaxf(sm[2], sm[3]));
  float p[5];
  float s = 0.f;
#pragma unroll
  for (int i = 0; i < 5; i++) {
    const int j = t + i * 256;
    p[i] = (j < 1089) ? __expf(v[i] - mx) : 0.f;
    s += p[i];
  }
#pragma unroll
  for (int off = 32; off; off >>= 1) s += __shfl_xor(s, off);
  __shared__ float ss[4];
  if ((t & 63) == 0) ss[t >> 6] = s;
  __syncthreads();
  const float inv = 1.f / (ss[0] + ss[1] + ss[2] + ss[3]);
#pragma unroll
  for (int i = 0; i < 5; i++) {
    const int j = t + i * 256;
    if (j < 1152) Pr[j] = f2bf(p[i] * inv);
  }
}

// ---------------------------------------------------------------------------
// Weight transpose (f32 -> bf16, W[K][N] -> Wt[N][K])
// ---------------------------------------------------------------------------
__global__ __launch_bounds__(256) void wtrans_kernel(const float* __restrict__ W,
    u16* __restrict__ Wt, int K, int N)
{
  __shared__ float tile[32][33];
  const int n0 = blockIdx.x * 32, k0 = blockIdx.y * 32;
  const int tx = threadIdx.x & 31, ty = threadIdx.x >> 5;
#pragma unroll
  for (int i = 0; i < 4; i++)
    tile[ty + 8 * i][tx] = W[(long)(k0 + ty + 8 * i) * N + n0 + tx];
  __syncthreads();
#pragma unroll
  for (int i = 0; i < 4; i++)
    Wt[(long)(n0 + ty + 8 * i) * K + k0 + tx] = f2bf(tile[tx][ty + 8 * i]);
}

__global__ __launch_bounds__(256) void catbias_kernel(const float* __restrict__ a,
    const float* __restrict__ b, const float* __restrict__ c, float* __restrict__ o)
{
  const int i = blockIdx.x * 256 + threadIdx.x;  // 3072
  o[i] = a[i]; o[3072 + i] = b[i]; o[6144 + i] = c[i];
}

// ---------------------------------------------------------------------------
// Unpatch (inverse unfold + crop) -> f32 output
// ---------------------------------------------------------------------------
__global__ __launch_bounds__(256) void unpatch_kernel(const float* __restrict__ X,
    float* __restrict__ out)
{
  const int idx = blockIdx.x * 256 + threadIdx.x;  // one per 4 floats
  const int w = (idx & 63) * 4;
  const int h = (idx >> 6) & 255;
  const int c = (idx >> 14) & 15;
  const int b = idx >> 18;
  const int ph = h >> 3, kh = h & 7, pw = w >> 3, kw = w & 7;
  const long row = (long)b * 1152 + ph * 33 + pw;
  const int d = c * 64 + kh * 8 + kw;
  const f32x4 v = *(const f32x4*)&X[row * 1024 + d];
  *(f32x4*)&out[((long)(b * 16 + c) * 256 + h) * 256 + w] = v;
}

// ---------------------------------------------------------------------------
extern "C" void kernel_launch(void* const* d_in, const int* in_sizes, int n_in,
                              void* d_out, int out_size, void* d_ws, size_t ws_size,
                              hipStream_t stream)
{
  (void)in_sizes; (void)n_in; (void)out_size; (void)ws_size;
  const float* dr_img = (const float*)d_in[0];
  const float* dr_ref = (const float*)d_in[1];
  const float* cl_ref = (const float*)d_in[2];
  const float* ln_g = (const float*)d_in[3];
  const float* ln_be = (const float*)d_in[4];
  const float* Wq = (const float*)d_in[5];
  const float* bq = (const float*)d_in[6];
  const float* Wk = (const float*)d_in[7];
  const float* bk = (const float*)d_in[8];
  const float* Wv = (const float*)d_in[9];
  const float* bv = (const float*)d_in[10];
  const float* Wo = (const float*)d_in[11];
  const float* bo = (const float*)d_in[12];
  const float* ffg = (const float*)d_in[13];
  const float* ffb = (const float*)d_in[14];
  const float* W1 = (const float*)d_in[15];
  const float* b1 = (const float*)d_in[16];
  const float* W2 = (const float*)d_in[17];
  const float* b2 = (const float*)d_in[18];

  const long R = 1152;                 // padded tokens per batch (9*128)
  const long MR = 4 * R;               // 4608 = 18*256

  char* ws = (char*)d_ws;
  size_t off = 0;
  auto alloc = [&](size_t bytes) -> void* {
    void* pp = ws + off;
    off += (bytes + 255) & ~(size_t)255;
    return pp;
  };
  float* x    = (float*)alloc((size_t)MR * 1024 * 4);
  u16* xkv_ln = (u16*)alloc((size_t)3 * MR * 1024 * 2);  // x_ln / k_ln(=FF h) / v_ln
  u16* qkv    = (u16*)alloc((size_t)3 * MR * 3072 * 2);  // q(=attn_out) / k / V^T[3072][4608]
  float* lgt  = (float*)alloc((size_t)4 * R * R * 4);
  u16* P      = (u16*)alloc((size_t)4 * R * R * 2);
  u16* Wqkv_t = (u16*)alloc((size_t)3 * 3072 * 1024 * 2);
  u16* Wo_t   = (u16*)alloc((size_t)1024 * 3072 * 2);
  u16* W1_t   = (u16*)alloc((size_t)1024 * 1024 * 2);
  u16* W2_t   = (u16*)alloc((size_t)1024 * 1024 * 2);
  float* bcat = (float*)alloc((size_t)3 * 3072 * 4);

  u16* x_ln = xkv_ln;
  u16* v_ln = xkv_ln + (size_t)2 * MR * 1024;
  u16* h    = xkv_ln + (size_t)MR * 1024;      // FF hidden aliases k_ln slot
  u16* qp   = qkv;
  u16* kp   = qkv + (size_t)MR * 3072;
  u16* vT   = qkv + (size_t)2 * MR * 3072;     // [3072][4608]
  u16* Wv_t = Wqkv_t + (size_t)2 * 3072 * 1024;

  wtrans_kernel<<<dim3(96, 32), 256, 0, stream>>>(Wq, Wqkv_t, 1024, 3072);
  wtrans_kernel<<<dim3(96, 32), 256, 0, stream>>>(Wk, Wqkv_t + (size_t)3072 * 1024, 1024, 3072);
  wtrans_kernel<<<dim3(96, 32), 256, 0, stream>>>(Wv, Wv_t, 1024, 3072);
  wtrans_kernel<<<dim3(32, 96), 256, 0, stream>>>(Wo, Wo_t, 3072, 1024);
  wtrans_kernel<<<dim3(32, 32), 256, 0, stream>>>(W1, W1_t, 1024, 1024);
  wtrans_kernel<<<dim3(32, 32), 256, 0, stream>>>(W2, W2_t, 1024, 1024);
  catbias_kernel<<<12, 256, 0, stream>>>(bq, bk, bv, bcat);

  patch_kernel<<<dim3(1152, 4), 256, 0, stream>>>(dr_img, x, 0);

  const long sAp = (long)MR * 1024;        // proj A slot stride
  const long sBp = (long)3072 * 1024;      // proj W slot stride
  const long sCp = (long)MR * 3072;        // proj C slot stride
  const long sQb = R * 3072;               // per-batch stride in qp/kp
  const long sLb = R * R;

  for (int shift = 0; shift < 4; shift++) {
    ln_kernel<<<(int)MR, 256, 0, stream>>>(x, ln_g, ln_be, x_ln);
    patch_ln_kernel<<<dim3(1152, 4), 256, 0, stream>>>(dr_ref, ln_g, ln_be, xkv_ln + sAp, shift);
    patch_ln_kernel<<<dim3(1152, 4), 256, 0, stream>>>(cl_ref, ln_g, ln_be, v_ln, shift);

    // Q/K projections, z-batched: [4608,1024] x [3072,1024]^T -> [4608,3072]
    gemm256<EPI_BF16_BIAS><<<dim3(12, 18, 2), 512, 131072, stream>>>(
        xkv_ln, Wqkv_t, qkv, bcat, 1024, 3072, sAp, sBp, sCp, 3072);

    // V^T projection (operand swap): [3072,1024] x [4608,1024]^T -> V^T[3072][4608]
    gemm256<EPI_BF16_BIASROW><<<dim3(18, 12, 1), 512, 131072, stream>>>(
        Wv_t, v_ln, vT, bv, 1024, (int)MR, 0, 0, 0, 0);

    // logits: per batch [1152,3072] x [1152,3072]^T -> [1152,1152] f32
    gemm128<EPI_F32><<<dim3(9, 9, 4), 512, 65536, stream>>>(
        qp, kp, lgt, nullptr, 3072, 3072, 1152, sQb, sQb, sLb);

    softmax_kernel<<<dim3(1152, 4), 256, 0, stream>>>(lgt, P);

    // PV: per batch [1152,1152] x V^T(ldb=4608, base offset b*1152) -> [1152,3072]
    gemm128<EPI_BF16><<<dim3(24, 9, 4), 512, 65536, stream>>>(
        P, vT, qp, nullptr, 1152, (int)MR, 3072, sLb, R, sQb);

    // out-proj + residual: [4608,3072] x [1024,3072]^T -> += x
    gemm128<EPI_F32_RES><<<dim3(8, 36, 1), 512, 65536, stream>>>(
        qp, Wo_t, x, bo, 3072, 3072, 1024, 0, 0, 0);

    ln_kernel<<<(int)MR, 256, 0, stream>>>(x, ffg, ffb, x_ln);
    gemm128<EPI_GELU><<<dim3(8, 36, 1), 512, 65536, stream>>>(
        x_ln, W1_t, h, b1, 1024, 1024, 1024, 0, 0, 0);
    gemm128<EPI_F32_RES><<<dim3(8, 36, 1), 512, 65536, stream>>>(
        h, W2_t, x, b2, 1024, 1024, 1024, 0, 0, 0);
  }

  unpatch_kernel<<<4096, 256, 0, stream>>>(x, (float*)d_out);
}